// Round 5
// baseline (504.157 us; speedup 1.0000x reference)
//
#include <hip/hip_runtime.h>
#include <hip/hip_bf16.h>
#include <math.h>

#define BSZ 4
#define SEQ 2048
#define DIMN 1024
#define NHEAD 16
#define DHEAD 64
#define MROWS (BSZ*SEQ)   // 8192

typedef __bf16 bf16x8 __attribute__((ext_vector_type(8)));
typedef float  f32x4  __attribute__((ext_vector_type(4)));
typedef float  f32x16 __attribute__((ext_vector_type(16)));
typedef float  fvec4  __attribute__((ext_vector_type(4)));
typedef short  s16x4  __attribute__((ext_vector_type(4)));
typedef short  s16x8  __attribute__((ext_vector_type(8)));

__device__ __forceinline__ short f2bf(float v) {
  __hip_bfloat16 b = __float2bfloat16(v);   // RNE
  return *reinterpret_cast<short*>(&b);
}
__device__ __forceinline__ float bf2f(short s) {
  __hip_bfloat16 b = *reinterpret_cast<__hip_bfloat16*>(&s);
  return __bfloat162float(b);
}

__device__ __forceinline__ void gld_lds16(const void* g, void* l) {
  __builtin_amdgcn_global_load_lds((const __attribute__((address_space(1))) void*)g,
                                   (__attribute__((address_space(3))) void*)l, 16, 0, 0);
}

// max of 16 via v_max3-friendly tree
__device__ __forceinline__ float max16(const f32x16 v) {
  float m0 = fmaxf(fmaxf(v[0], v[1]),  v[2]);
  float m1 = fmaxf(fmaxf(v[3], v[4]),  v[5]);
  float m2 = fmaxf(fmaxf(v[6], v[7]),  v[8]);
  float m3 = fmaxf(fmaxf(v[9], v[10]), v[11]);
  float m4 = fmaxf(fmaxf(v[12], v[13]), v[14]);
  float m5 = fmaxf(v[15], m0);
  float m6 = fmaxf(fmaxf(m1, m2), m3);
  return fmaxf(fmaxf(m4, m5), m6);
}

// 0.125 (1/sqrt(DH)) * log2(e): folds softmax base-2 conversion into Wq/bq.
#define QSC 0.18033688011112042f

// ---------------------------------------------------------------------------
// pack_w4: all four weight packs in one launch. y=0 Wq*QSC hi, 1 Wk hi,
// 2 Wv hi, 3 Wo hi+lo.
// ---------------------------------------------------------------------------
__global__ __launch_bounds__(256) void pack_w4(
    const float* __restrict__ Wq, const float* __restrict__ Wk,
    const float* __restrict__ Wv, const float* __restrict__ Wo,
    short* __restrict__ WQh, short* __restrict__ WKh,
    short* __restrict__ WVh, short* __restrict__ WOh, short* __restrict__ WOl,
    long n)
{
  long i = ((long)blockIdx.x * 256 + threadIdx.x) * 4;
  if (i >= n) return;
  int which = blockIdx.y;
  if (which == 3) {
    fvec4 v = *(const fvec4*)&Wo[i];
    s16x4 h, l;
#pragma unroll
    for (int j = 0; j < 4; ++j) {
      short hb = f2bf(v[j]);
      h[j] = hb;
      l[j] = f2bf(v[j] - bf2f(hb));
    }
    *(s16x4*)&WOh[i] = h;
    *(s16x4*)&WOl[i] = l;
  } else {
    const float* src = which == 0 ? Wq : (which == 1 ? Wk : Wv);
    short* dst = which == 0 ? WQh : (which == 1 ? WKh : WVh);
    float sc = which == 0 ? QSC : 1.f;
    fvec4 v = *(const fvec4*)&src[i];
    s16x4 h;
#pragma unroll
    for (int j = 0; j < 4; ++j) h[j] = f2bf(v[j] * sc);
    *(s16x4*)&dst[i] = h;
  }
}

// pack_hi3: query/key/value -> bf16 hi planes, one launch (y selects).
__global__ __launch_bounds__(256) void pack_hi3(
    const float* __restrict__ q, const float* __restrict__ k,
    const float* __restrict__ v,
    short* __restrict__ xq, short* __restrict__ xk, short* __restrict__ xv,
    long n)
{
  long i = ((long)blockIdx.x * 256 + threadIdx.x) * 4;
  if (i >= n) return;
  const float* src = blockIdx.y == 0 ? q : (blockIdx.y == 1 ? k : v);
  short* dst = blockIdx.y == 0 ? xq : (blockIdx.y == 1 ? xk : xv);
  fvec4 x = *(const fvec4*)&src[i];
  s16x4 h;
#pragma unroll
  for (int j = 0; j < 4; ++j) h[j] = f2bf(x[j]);
  *(s16x4*)&dst[i] = h;
}

__global__ __launch_bounds__(256) void maskbias_k(
    const int* __restrict__ mask, float* __restrict__ mb, int n)
{
  int i = blockIdx.x * 256 + threadIdx.x;
  if (i < n) mb[i] = mask[i] ? 0.f : -1e30f;
}

// per-(b, 128-key-chunk) all-valid flags (64 chunks)
__global__ __launch_bounds__(64) void mask_flags(
    const int* __restrict__ mask, int* __restrict__ flg)
{
  int c = blockIdx.x;               // 0..63: b = c>>4, chunk = c&15
  int base = (c >> 4) * SEQ + (c & 15) * 128;
  int m0 = mask[base + threadIdx.x];
  int m1 = mask[base + 64 + threadIdx.x];
  unsigned long long bal = __ballot(m0 != 0 && m1 != 0);
  if (threadIdx.x == 0) flg[c] = (bal == ~0ull) ? 1 : 0;
}

// ---------------------------------------------------------------------------
// Single-plane bf16 MFMA GEMM, XOR-swizzled LDS. C = A[M,K] @ B[N,K]^T + bias
// mode 0: f32 -> Cf. mode 1: bf16 -> Cb ([M,N]). mode 2: bf16 -> Cb in
// VT layout [(b*16+hd)*64+dd][SEQ] (fused V transpose).
// ---------------------------------------------------------------------------
__global__ __launch_bounds__(256) void gemm_h(
    const short* __restrict__ A, const short* __restrict__ B,
    const float* __restrict__ bias, float bscale,
    float* __restrict__ Cf, short* __restrict__ Cb,
    int M, int N, int K, int mode)
{
  __shared__ __align__(16) short sA[128*32];   // 8 KB
  __shared__ __align__(16) short sB[128*32];
  const int t = threadIdx.x;
  const int ln = t & 15, quad = (t & 63) >> 4, w = t >> 6;
  const int wm = w >> 1, wn = w & 1;
  const int m0 = blockIdx.y * 128, n0 = blockIdx.x * 128;
  const int lrow = t >> 2;
  const int lko = (((t & 3) ^ ((t >> 3) & 3))) * 8;   // XOR-swizzled k-chunk
  const int fsw = ((ln >> 1) & 3);                     // frag-read swizzle key
  f32x4 acc[4][4];
#pragma unroll
  for (int i = 0; i < 4; ++i)
#pragma unroll
    for (int j = 0; j < 4; ++j) acc[i][j] = (f32x4){0.f,0.f,0.f,0.f};

  for (int k0 = 0; k0 < K; k0 += 32) {
    __syncthreads();
#pragma unroll
    for (int u = 0; u < 2; ++u) {
      int row = u*64 + lrow;
      gld_lds16(A + (size_t)(m0+row)*K + k0 + lko, sA + u*2048 + t*8);
      gld_lds16(B + (size_t)(n0+row)*K + k0 + lko, sB + u*2048 + t*8);
    }
    __syncthreads();
    bf16x8 af[4], bfr[4];
#pragma unroll
    for (int mt = 0; mt < 4; ++mt)
      af[mt] = *(bf16x8*)&sA[(wm*64 + mt*16 + ln)*32 + (quad ^ fsw)*8];
#pragma unroll
    for (int nt = 0; nt < 4; ++nt)
      bfr[nt] = *(bf16x8*)&sB[(wn*64 + nt*16 + ln)*32 + (quad ^ fsw)*8];
#pragma unroll
    for (int mt = 0; mt < 4; ++mt)
#pragma unroll
      for (int nt = 0; nt < 4; ++nt)
        acc[mt][nt] = __builtin_amdgcn_mfma_f32_16x16x32_bf16(af[mt], bfr[nt], acc[mt][nt], 0, 0, 0);
  }
#pragma unroll
  for (int nt = 0; nt < 4; ++nt) {
    int col = n0 + wn*64 + nt*16 + ln;
    float bv = bias[col] * bscale;
    if (mode == 2) {
      int hd = col >> 6, dd = col & 63;
#pragma unroll
      for (int mt = 0; mt < 4; ++mt) {
        int sg = m0 + wm*64 + mt*16 + quad*4;
        int b = sg >> 11, s = sg & 2047;
        s16x4 h;
#pragma unroll
        for (int r = 0; r < 4; ++r) h[r] = f2bf(acc[mt][nt][r] + bv);
        *(s16x4*)&Cb[((size_t)((b*16 + hd)*64 + dd))*SEQ + s] = h;
      }
    } else {
#pragma unroll
      for (int mt = 0; mt < 4; ++mt)
#pragma unroll
        for (int r = 0; r < 4; ++r) {
          int row = m0 + wm*64 + mt*16 + quad*4 + r;
          float val = acc[mt][nt][r] + bv;
          if (mode == 0) Cf[(size_t)row*N + col] = val;
          else           Cb[(size_t)row*N + col] = f2bf(val);
        }
    }
  }
}

// ---------------------------------------------------------------------------
// 3-term split-bf16 GEMM (O-projection), XOR-swizzled LDS.
// ---------------------------------------------------------------------------
__global__ __launch_bounds__(256) void gemm_sp(
    const short* __restrict__ Ah, const short* __restrict__ Al,
    const short* __restrict__ Bh, const short* __restrict__ Bl,
    const float* __restrict__ bias, float bscale,
    float* __restrict__ C, int M, int N, int K)
{
  __shared__ __align__(16) short sA[2*128*32];   // 16 KB
  __shared__ __align__(16) short sB[2*128*32];
  const int t = threadIdx.x;
  const int ln = t & 15, quad = (t & 63) >> 4, w = t >> 6;
  const int wm = w >> 1, wn = w & 1;
  const int m0 = blockIdx.y * 128, n0 = blockIdx.x * 128;
  const int lrow = t >> 2;
  const int lko = (((t & 3) ^ ((t >> 3) & 3))) * 8;
  const int fsw = ((ln >> 1) & 3);
  f32x4 acc[4][4];
#pragma unroll
  for (int i = 0; i < 4; ++i)
#pragma unroll
    for (int j = 0; j < 4; ++j) acc[i][j] = (f32x4){0.f,0.f,0.f,0.f};

  for (int k0 = 0; k0 < K; k0 += 32) {
    __syncthreads();
#pragma unroll
    for (int u = 0; u < 2; ++u) {
      int row = u*64 + lrow;
      gld_lds16(Ah + (size_t)(m0+row)*K + k0 + lko, sA + u*2048 + t*8);
      gld_lds16(Al + (size_t)(m0+row)*K + k0 + lko, sA + 4096 + u*2048 + t*8);
      gld_lds16(Bh + (size_t)(n0+row)*K + k0 + lko, sB + u*2048 + t*8);
      gld_lds16(Bl + (size_t)(n0+row)*K + k0 + lko, sB + 4096 + u*2048 + t*8);
    }
    __syncthreads();
    bf16x8 ah[4], al[4], bh[4], bl[4];
#pragma unroll
    for (int mt = 0; mt < 4; ++mt) {
      int r = wm*64 + mt*16 + ln;
      ah[mt] = *(bf16x8*)&sA[r*32 + (quad ^ fsw)*8];
      al[mt] = *(bf16x8*)&sA[4096 + r*32 + (quad ^ fsw)*8];
    }
#pragma unroll
    for (int nt = 0; nt < 4; ++nt) {
      int r = wn*64 + nt*16 + ln;
      bh[nt] = *(bf16x8*)&sB[r*32 + (quad ^ fsw)*8];
      bl[nt] = *(bf16x8*)&sB[4096 + r*32 + (quad ^ fsw)*8];
    }
#pragma unroll
    for (int mt = 0; mt < 4; ++mt)
#pragma unroll
      for (int nt = 0; nt < 4; ++nt) {
        acc[mt][nt] = __builtin_amdgcn_mfma_f32_16x16x32_bf16(ah[mt], bh[nt], acc[mt][nt], 0, 0, 0);
        acc[mt][nt] = __builtin_amdgcn_mfma_f32_16x16x32_bf16(ah[mt], bl[nt], acc[mt][nt], 0, 0, 0);
        acc[mt][nt] = __builtin_amdgcn_mfma_f32_16x16x32_bf16(al[mt], bh[nt], acc[mt][nt], 0, 0, 0);
      }
  }
#pragma unroll
  for (int nt = 0; nt < 4; ++nt) {
    float bv = bias[n0 + wn*64 + nt*16 + ln] * bscale;
#pragma unroll
    for (int mt = 0; mt < 4; ++mt)
#pragma unroll
      for (int r = 0; r < 4; ++r)
        C[(size_t)(m0 + wm*64 + mt*16 + quad*4 + r)*N + (n0 + wn*64 + nt*16 + ln)] =
            acc[mt][nt][r] + bv;
  }
}

// ---------------------------------------------------------------------------
// Flash attention v8: v7 structure + (a) sacc CLASS-PINNED to arch VGPRs via
// empty "+v" asm (eliminates v_accvgpr_read/write shuttles around the
// softmax VALU ops -- the invariant ~90us VALU cost across v5/v6/v7), and
// (b) l-sum computed by an extra ones-MFMA per kcs step on the idle matrix
// pipe (replaces 64 v_add + shuffle; P-frags hold the full 128-kc row so no
// cross-lane reduce is needed). o_acc/acc_l/qf deliberately NOT pinned:
// only MFMA touches them in the common path, so AGPR residency is free.
// ---------------------------------------------------------------------------
__global__ __launch_bounds__(256, 2) void attn_v8(
    const short* __restrict__ QB, const short* __restrict__ KB,
    const short* __restrict__ VT, const float* __restrict__ mb,
    const int* __restrict__ flg,
    short* __restrict__ CTXh, short* __restrict__ CTXl)
{
  __shared__ __align__(16) short lds[16384];   // 32 KB
  short* sK = lds;           // [128 kc][64 k], granule ^(kc&7); Q staged here first
  short* sV = lds + 8192;    // [64 d][128 kc], granule ^(d&15)

  const int t = threadIdx.x;
  const int l31 = t & 31, hi = (t >> 5) & 1, w = t >> 6;
  const int gb = blockIdx.x;
  const int chunk = gb >> 3, qt128 = chunk & 15, bh = ((chunk >> 4) << 3) + (gb & 7);
  const int b = bh >> 4, hd = bh & 15;

  // hoisted swizzled LDS read offsets (elements)
  int offK[4], offV[8];
#pragma unroll
  for (int ks = 0; ks < 4; ++ks)
    offK[ks] = l31*64 + ((ks*2 + hi) ^ (l31 & 7))*8;
#pragma unroll
  for (int kcs = 0; kcs < 8; ++kcs)
    offV[kcs] = l31*128 + ((kcs*2 + hi) ^ (l31 & 15))*8;

  // ones B... A-operand fragment for the l-sum MFMA (bf16 1.0 x8)
  bf16x8 onesf;
  {
    union { short s[8]; bf16x8 v; } u;
#pragma unroll
    for (int i = 0; i < 8; ++i) u.s[i] = (short)0x3F80;
    onesf = u.v;
  }

  // stage Q [128 q][64 k] into sK region, pull B-frags, then region is free
#pragma unroll
  for (int i = 0; i < 4; ++i) {
    int u = i*256 + t;
    int row = u >> 3, gr = (u & 7) ^ (row & 7);
    gld_lds16(QB + ((size_t)(b*SEQ + qt128*128 + row))*DIMN + hd*64 + gr*8,
              sK + u*8);
  }
  __syncthreads();
  const int q = w*32 + l31;
  bf16x8 qf[4];
#pragma unroll
  for (int ks = 0; ks < 4; ++ks)
    qf[ks] = *(const bf16x8*)&sK[w*2048 + offK[ks]];

  f32x16 o_acc[2] = {};          // O^T: col = own q (l31), rows d
  f32x16 acc_l = {};             // row-sum accumulator (all 16 rows equal)
  float m_run = 0.f;

  for (int kt = 0; kt < SEQ/128; ++kt) {
    __syncthreads();   // all waves done with sK/sV (and qf reads on kt=0)
#pragma unroll
    for (int i = 0; i < 4; ++i) {
      int u = i*256 + t;
      { int row = u >> 3, gr = (u & 7) ^ (row & 7);
        gld_lds16(KB + ((size_t)(b*SEQ + kt*128 + row))*DIMN + hd*64 + gr*8,
                  sK + u*8); }
      { int d = u >> 4, gr = (u & 15) ^ (d & 15);
        gld_lds16(VT + ((size_t)(bh*64 + d))*SEQ + kt*128 + gr*8,
                  sV + u*8); }
    }
    __syncthreads();

    // S^T[kc][q], biased: init C = -m_run so sacc = S - m_run after MFMA.
    f32x16 sacc[4];
    {
      float mneg = -m_run;
#pragma unroll
      for (int mt = 0; mt < 4; ++mt) {
#pragma unroll
        for (int r = 0; r < 16; ++r) sacc[mt][r] = mneg;
        asm("" : "+v"(sacc[mt]));        // pin to arch VGPRs (no AGPR shuttle)
      }
    }

    __builtin_amdgcn_s_setprio(1);
#pragma unroll
    for (int ks = 0; ks < 4; ++ks)
#pragma unroll
      for (int mt = 0; mt < 4; ++mt) {
        bf16x8 kf = *(const bf16x8*)&sK[mt*2048 + offK[ks]];
        sacc[mt] = __builtin_amdgcn_mfma_f32_32x32x16_bf16(kf, qf[ks], sacc[mt], 0, 0, 0);
      }
    __builtin_amdgcn_s_setprio(0);
#pragma unroll
    for (int mt = 0; mt < 4; ++mt)
      asm("" : "+v"(sacc[mt]));          // pin again post-MFMA

    if (!flg[b*16 + kt]) {       // mask slow path (bench: all-valid fast path)
#pragma unroll
      for (int mt = 0; mt < 4; ++mt)
#pragma unroll
        for (int r = 0; r < 16; ++r)
          sacc[mt][r] += mb[b*SEQ + kt*128 + mt*32 + (r&3) + 8*(r>>2) + 4*hi];
    }

    // online softmax (biased): lane owns col q = l31; lane^32 has same q,
    // other 64 kc rows.
    float tb = fmaxf(fmaxf(max16(sacc[0]), max16(sacc[1])),
                     fmaxf(max16(sacc[2]), max16(sacc[3])));
    tb = fmaxf(tb, __shfl_xor(tb, 32));

    if (__builtin_expect(!__all(tb <= 8.f), 0)) {
      // rescale path: delta = max(0, tb); m_run += delta
      float delta = fmaxf(tb, 0.f);
      float al = exp2f(-delta);
#pragma unroll
      for (int dt = 0; dt < 2; ++dt)
#pragma unroll
        for (int r = 0; r < 16; ++r) o_acc[dt][r] *= al;
#pragma unroll
      for (int r = 0; r < 16; ++r) acc_l[r] *= al;
      m_run += delta;
#pragma unroll
      for (int mt = 0; mt < 4; ++mt)
#pragma unroll
        for (int r = 0; r < 16; ++r)
          sacc[mt][r] = exp2f(sacc[mt][r] - delta);
    } else {
      // deferred (common): exp directly on biased acc, P <= 2^8
#pragma unroll
      for (int mt = 0; mt < 4; ++mt)
#pragma unroll
        for (int r = 0; r < 16; ++r)
          sacc[mt][r] = exp2f(sacc[mt][r]);
    }

    // P -> bf16 B-frags in-register; O^T += mfma(V^T, P); l += mfma(1, P).
    __builtin_amdgcn_s_setprio(1);
#pragma unroll
    for (int mt = 0; mt < 4; ++mt) {
#pragma unroll
      for (int h = 0; h < 2; ++h) {
        unsigned w0, w1, w2, w3;
        {
          float a0 = sacc[mt][h*8+0], a1 = sacc[mt][h*8+1];
          float a2 = sacc[mt][h*8+2], a3 = sacc[mt][h*8+3];
          float a4 = sacc[mt][h*8+4], a5 = sacc[mt][h*8+5];
          float a6 = sacc[mt][h*8+6], a7 = sacc[mt][h*8+7];
          asm("v_cvt_pk_bf16_f32 %0, %1, %2" : "=v"(w0) : "v"(a0), "v"(a1));
          asm("v_cvt_pk_bf16_f32 %0, %1, %2" : "=v"(w1) : "v"(a2), "v"(a3));
          asm("v_cvt_pk_bf16_f32 %0, %1, %2" : "=v"(w2) : "v"(a4), "v"(a5));
          asm("v_cvt_pk_bf16_f32 %0, %1, %2" : "=v"(w3) : "v"(a6), "v"(a7));
        }
        asm("v_permlane32_swap_b32 %0, %1" : "+v"(w0), "+v"(w2));
        asm("v_permlane32_swap_b32 %0, %1" : "+v"(w1), "+v"(w3));
        union { unsigned u[4]; bf16x8 v; } pu;
        pu.u[0] = w0; pu.u[1] = w1; pu.u[2] = w2; pu.u[3] = w3;
        const int kcs = mt*2 + h;      // 16-wide kc step, 0..7
#pragma unroll
        for (int dt = 0; dt < 2; ++dt) {
          bf16x8 vf = *(const bf16x8*)&sV[dt*4096 + offV[kcs]];
          o_acc[dt] = __builtin_amdgcn_mfma_f32_32x32x16_bf16(vf, pu.v, o_acc[dt], 0, 0, 0);
        }
        acc_l = __builtin_amdgcn_mfma_f32_32x32x16_bf16(onesf, pu.v, acc_l, 0, 0, 0);
      }
    }
    __builtin_amdgcn_s_setprio(0);
  }

  // epilogue: lane holds O^T col q (its own), rows d = dt*32 + r2 + 8*rg + 4*hi
  float lsum = acc_l[0];
  float invl = (lsum > 0.f) ? 1.f / lsum : 0.f;
  const size_t rowbase = (size_t)(b*SEQ + qt128*128 + q)*DIMN + hd*64;
#pragma unroll
  for (int dt = 0; dt < 2; ++dt)
#pragma unroll
    for (int rg = 0; rg < 4; ++rg) {
      s16x4 hq, lq;
#pragma unroll
      for (int r2 = 0; r2 < 4; ++r2) {
        float val = o_acc[dt][rg*4 + r2] * invl;
        short hb = f2bf(val);
        hq[r2] = hb;
        lq[r2] = f2bf(val - bf2f(hb));
      }
      size_t idx = rowbase + dt*32 + rg*8 + hi*4;
      *(s16x4*)&CTXh[idx] = hq;
      *(s16x4*)&CTXl[idx] = lq;
    }
}

// ===========================================================================
// Fallback fp32 path for small ws_size.
// ===========================================================================
__global__ __launch_bounds__(256) void gemm_bt(
    const float* __restrict__ X, const float* __restrict__ W,
    const float* __restrict__ bias, float* __restrict__ C,
    int M, int N, int K)
{
  __shared__ __align__(16) float Xs[16][68];
  __shared__ __align__(16) float Ws[16][68];
  const int t  = threadIdx.x;
  const int tx = t & 15, ty = t >> 4;
  const int m0 = blockIdx.y << 6, n0 = blockIdx.x << 6;
  const int ldr = t >> 2;
  const int lk  = (t & 3) << 2;
  float acc[4][4] = {{0.f}};
  const float* Xp = X + (size_t)(m0 + ldr) * K + lk;
  const float* Wp = W + (size_t)(n0 + ldr) * K + lk;
  for (int k0 = 0; k0 < K; k0 += 16) {
    float4 xa = *(const float4*)(Xp + k0);
    float4 wa = *(const float4*)(Wp + k0);
    Xs[lk+0][ldr]=xa.x; Xs[lk+1][ldr]=xa.y; Xs[lk+2][ldr]=xa.z; Xs[lk+3][ldr]=xa.w;
    Ws[lk+0][ldr]=wa.x; Ws[lk+1][ldr]=wa.y; Ws[lk+2][ldr]=wa.z; Ws[lk+3][ldr]=wa.w;
    __syncthreads();
#pragma unroll
    for (int kk = 0; kk < 16; ++kk) {
      float4 a4 = *(const float4*)&Xs[kk][ty<<2];
      float4 b4 = *(const float4*)&Ws[kk][tx<<2];
      float av[4] = {a4.x, a4.y, a4.z, a4.w};
      float bv[4] = {b4.x, b4.y, b4.z, b4.w};
#pragma unroll
      for (int i = 0; i < 4; ++i)
#pragma unroll
        for (int j = 0; j < 4; ++j)
          acc[i][j] = fmaf(av[i], bv[j], acc[i][j]);
    }
    __syncthreads();
  }
  float4 bb4 = *(const float4*)&bias[n0 + (tx<<2)];
  const float bv[4] = {bb4.x, bb4.y, bb4.z, bb4.w};
#pragma unroll
  for (int i = 0; i < 4; ++i) {
    float4 o;
    o.x = acc[i][0]+bv[0]; o.y = acc[i][1]+bv[1];
    o.z = acc[i][2]+bv[2]; o.w = acc[i][3]+bv[3];
    *(float4*)&C[(size_t)(m0 + (ty<<2) + i) * N + n0 + (tx<<2)] = o;
  }
}

__global__ __launch_bounds__(256) void attn_fwd(
    const float* __restrict__ Q, const float* __restrict__ Kbuf,
    const float* __restrict__ Vbuf, const int* __restrict__ mask,
    float* __restrict__ CTX)
{
  __shared__ __align__(16) float Qs[64][68];
  __shared__ __align__(16) float KPs[64][68];
  __shared__ __align__(16) float Vs[64][68];
  const int t  = threadIdx.x;
  const int tx = t & 15, ty = t >> 4;
  const int qt = blockIdx.x;
  const int bh = blockIdx.y;
  const int b  = bh >> 4, h = bh & 15;
  const int ldr = t >> 2;
  const int lcb = (t & 3) << 2;
  const float* Qp = Q + (size_t)(b*SEQ + (qt<<6)) * DIMN + h*DHEAD;
#pragma unroll
  for (int u = 0; u < 4; ++u) {
    int kb = lcb + (u<<4);
    float4 q4 = *(const float4*)(Qp + (size_t)ldr*DIMN + kb);
    Qs[kb+0][ldr]=q4.x; Qs[kb+1][ldr]=q4.y; Qs[kb+2][ldr]=q4.z; Qs[kb+3][ldr]=q4.w;
  }
  float mrow[4], lsum[4], o[4][4];
#pragma unroll
  for (int i = 0; i < 4; ++i) {
    mrow[i] = -1e30f; lsum[i] = 0.f;
#pragma unroll
    for (int j = 0; j < 4; ++j) o[i][j] = 0.f;
  }
  const int qrow0 = ty << 2;
  const int col0  = tx << 2;
  for (int kt = 0; kt < SEQ/64; ++kt) {
    __syncthreads();
    const float* Kp = Kbuf + (size_t)(b*SEQ + (kt<<6)) * DIMN + h*DHEAD;
    const float* Vp = Vbuf + (size_t)(b*SEQ + (kt<<6)) * DIMN + h*DHEAD;
#pragma unroll
    for (int u = 0; u < 4; ++u) {
      int kb = lcb + (u<<4);
      float4 k4 = *(const float4*)(Kp + (size_t)ldr*DIMN + kb);
      KPs[kb+0][ldr]=k4.x; KPs[kb+1][ldr]=k4.y; KPs[kb+2][ldr]=k4.z; KPs[kb+3][ldr]=k4.w;
      float4 v4 = *(const float4*)(Vp + (size_t)ldr*DIMN + kb);
      *(float4*)&Vs[ldr][kb] = v4;
    }
    __syncthreads();
    float s[4][4] = {{0.f}};
#pragma unroll 8
    for (int kk = 0; kk < 64; ++kk) {
      float4 a4 = *(const float4*)&Qs[kk][qrow0];
      float4 b4 = *(const float4*)&KPs[kk][col0];
      float av[4] = {a4.x, a4.y, a4.z, a4.w};
      float bv[4] = {b4.x, b4.y, b4.z, b4.w};
#pragma unroll
      for (int i = 0; i < 4; ++i)
#pragma unroll
        for (int j = 0; j < 4; ++j)
          s[i][j] = fmaf(av[i], bv[j], s[i][j]);
    }
    int mk[4];
#pragma unroll
    for (int j = 0; j < 4; ++j) mk[j] = mask[b*SEQ + (kt<<6) + col0 + j];
    float p[4][4];
#pragma unroll
    for (int i = 0; i < 4; ++i) {
#pragma unroll
      for (int j = 0; j < 4; ++j)
        s[i][j] = mk[j] ? s[i][j]*0.125f : -1e30f;
      float tm = fmaxf(fmaxf(s[i][0], s[i][1]), fmaxf(s[i][2], s[i][3]));
#pragma unroll
      for (int off = 8; off >= 1; off >>= 1)
        tm = fmaxf(tm, __shfl_xor(tm, off, 64));
      float mnew  = fmaxf(mrow[i], tm);
      float aa = __expf(mrow[i] - mnew);
      mrow[i] = mnew;
      float rsum = 0.f;
#pragma unroll
      for (int j = 0; j < 4; ++j) {
        float pv = __expf(s[i][j] - mnew);
        p[i][j] = pv; rsum += pv;
      }
#pragma unroll
      for (int off = 8; off >= 1; off >>= 1)
        rsum += __shfl_xor(rsum, off, 64);
      lsum[i] = lsum[i]*aa + rsum;
#pragma unroll
      for (int j = 0; j < 4; ++j) o[i][j] *= aa;
    }
    __syncthreads();
#pragma unroll
    for (int i = 0; i < 4; ++i)
#pragma unroll
      for (int j = 0; j < 4; ++j)
        KPs[col0 + j][qrow0 + i] = p[i][j];
    __syncthreads();
#pragma unroll 8
    for (int kk = 0; kk < 64; ++kk) {
      float4 a4 = *(const float4*)&KPs[kk][qrow0];
      float4 v4 = *(const float4*)&Vs[kk][col0];
      float av[4] = {a4.x, a4.y, a4.z, a4.w};
      float vv[4] = {v4.x, v4.y, v4.z, v4.w};
#pragma unroll
      for (int i = 0; i < 4; ++i)
#pragma unroll
        for (int j = 0; j < 4; ++j)
          o[i][j] = fmaf(av[i], vv[j], o[i][j]);
    }
  }
  float* Cp = CTX + (size_t)(b*SEQ + (qt<<6)) * DIMN + h*DHEAD;
#pragma unroll
  for (int i = 0; i < 4; ++i) {
    float inv = lsum[i] > 0.f ? 1.0f/lsum[i] : 0.f;
    float4 ov;
    ov.x = o[i][0]*inv; ov.y = o[i][1]*inv;
    ov.z = o[i][2]*inv; ov.w = o[i][3]*inv;
    *(float4*)(Cp + (size_t)(qrow0 + i)*DIMN + col0) = ov;
  }
}

// ---------------------------------------------------------------------------
extern "C" void kernel_launch(void* const* d_in, const int* in_sizes, int n_in,
                              void* d_out, int out_size, void* d_ws, size_t ws_size,
                              hipStream_t stream)
{
  const float* query = (const float*)d_in[0];
  const float* key   = (const float*)d_in[1];
  const float* value = (const float*)d_in[2];
  const int*   mask  = (const int*)d_in[3];
  const float* Wq = (const float*)d_in[4];
  const float* bq = (const float*)d_in[5];
  const float* Wk = (const float*)d_in[6];
  const float* bk = (const float*)d_in[7];
  const float* Wv = (const float*)d_in[8];
  const float* bv = (const float*)d_in[9];
  const float* Wo = (const float*)d_in[10];
  const float* bo = (const float*)d_in[11];
  float* out = (float*)d_out;

  const size_t E  = (size_t)MROWS * DIMN;   // 8,388,608
  const size_t WE = (size_t)DIMN * DIMN;    // 1,048,576

  // ws layout (bytes)
  const size_t o_XB   = 5*WE*2;                 // weights: 10 MB
  const size_t o_QB   = o_XB   + 3*E*2;         // XBq,XBk,XBv: 48 MB
  const size_t o_KB   = o_QB   + E*2;
  const size_t o_VT   = o_KB   + E*2;
  const size_t o_CTXh = o_VT   + E*2;
  const size_t o_CTXl = o_CTXh + E*2;
  const size_t o_MB   = o_CTXl + E*2;
  const size_t o_FLG  = o_MB   + MROWS*4;
  const size_t NEED   = o_FLG  + 64*4;          // ~138 MB

  if (ws_size < NEED) {
    const size_t n = E;
    float* Qb = (float*)d_ws;
    float* Kb = Qb + n;
    float* Vb = Kb + n;
    float* Cb = Vb + n;
    dim3 gg(DIMN/64, MROWS/64), blk(256);
    hipLaunchKernelGGL(gemm_bt, gg, blk, 0, stream, query, Wq, bq, Qb, MROWS, DIMN, DIMN);
    hipLaunchKernelGGL(gemm_bt, gg, blk, 0, stream, key,   Wk, bk, Kb, MROWS, DIMN, DIMN);
    hipLaunchKernelGGL(gemm_bt, gg, blk, 0, stream, value, Wv, bv, Vb, MROWS, DIMN, DIMN);
    dim3 ga(SEQ/64, BSZ*NHEAD);
    hipLaunchKernelGGL(attn_fwd, ga, blk, 0, stream, Qb, Kb, Vb, mask, Cb);
    hipLaunchKernelGGL(gemm_bt, gg, blk, 0, stream, Cb, Wo, bo, out, MROWS, DIMN, DIMN);
    return;
  }

  char* Wp = (char*)d_ws;
  short* WQh = (short*)Wp;
  short* WKh = WQh + WE;
  short* WVh = WQh + 2*WE;
  short* WOh = WQh + 3*WE;
  short* WOl = WQh + 4*WE;
  short* XBq  = (short*)(Wp + o_XB);
  short* XBk  = XBq + E;
  short* XBv  = XBk + E;
  short* QB   = (short*)(Wp + o_QB);
  short* KB   = (short*)(Wp + o_KB);
  short* VT   = (short*)(Wp + o_VT);
  short* CTXh = (short*)(Wp + o_CTXh);
  short* CTXl = (short*)(Wp + o_CTXl);
  float* MB   = (float*)(Wp + o_MB);
  int*   FLG  = (int*)(Wp + o_FLG);

  dim3 blk(256);
  dim3 gW(WE/1024, 4), gX(E/1024, 3);
  dim3 gg(DIMN/128, MROWS/128);       // (8, 64)
  dim3 gat(BSZ*NHEAD*SEQ/128);        // 1024

  hipLaunchKernelGGL(pack_w4, gW, blk, 0, stream, Wq, Wk, Wv, Wo,
                     WQh, WKh, WVh, WOh, WOl, (long)WE);
  hipLaunchKernelGGL(maskbias_k, dim3(MROWS/256), blk, 0, stream, mask, MB, MROWS);
  hipLaunchKernelGGL(mask_flags, dim3(64), dim3(64), 0, stream, mask, FLG);
  hipLaunchKernelGGL(pack_hi3, gX, blk, 0, stream, query, key, value,
                     XBq, XBk, XBv, (long)E);

  hipLaunchKernelGGL(gemm_h, gg, blk, 0, stream, XBq, WQh, bq, QSC,
                     (float*)nullptr, QB, MROWS, DIMN, DIMN, 1);
  hipLaunchKernelGGL(gemm_h, gg, blk, 0, stream, XBk, WKh, bk, 1.f,
                     (float*)nullptr, KB, MROWS, DIMN, DIMN, 1);
  hipLaunchKernelGGL(gemm_h, gg, blk, 0, stream, XBv, WVh, bv, 1.f,
                     (float*)nullptr, VT, MROWS, DIMN, DIMN, 2);

  hipLaunchKernelGGL(attn_v8, gat, blk, 0, stream, QB, KB, VT, MB, FLG, CTXh, CTXl);

  hipLaunchKernelGGL(gemm_sp, gg, blk, 0, stream, CTXh, CTXl, WOh, WOl, bo, 1.f,
                     out, MROWS, DIMN, DIMN);
}

// Round 6
// 417.593 us; speedup vs baseline: 1.2073x; 1.2073x over previous
//
#include <hip/hip_runtime.h>
#include <hip/hip_bf16.h>
#include <math.h>

#define BSZ 4
#define SEQ 2048
#define DIMN 1024
#define NHEAD 16
#define DHEAD 64
#define MROWS (BSZ*SEQ)   // 8192

typedef __bf16 bf16x8 __attribute__((ext_vector_type(8)));
typedef float  f32x4  __attribute__((ext_vector_type(4)));
typedef float  f32x16 __attribute__((ext_vector_type(16)));
typedef float  fvec4  __attribute__((ext_vector_type(4)));
typedef short  s16x4  __attribute__((ext_vector_type(4)));
typedef short  s16x8  __attribute__((ext_vector_type(8)));

__device__ __forceinline__ short f2bf(float v) {
  __hip_bfloat16 b = __float2bfloat16(v);   // RNE
  return *reinterpret_cast<short*>(&b);
}
__device__ __forceinline__ float bf2f(short s) {
  __hip_bfloat16 b = *reinterpret_cast<__hip_bfloat16*>(&s);
  return __bfloat162float(b);
}

__device__ __forceinline__ void gld_lds16(const void* g, void* l) {
  __builtin_amdgcn_global_load_lds((const __attribute__((address_space(1))) void*)g,
                                   (__attribute__((address_space(3))) void*)l, 16, 0, 0);
}

// 0.125 (1/sqrt(DH)) * log2(e): folds softmax base-2 conversion into Wq/bq.
#define QSC 0.18033688011112042f

// ---------------------------------------------------------------------------
// pack_w4: all four weight packs in one launch. y=0 Wq*QSC hi, 1 Wk hi,
// 2 Wv hi, 3 Wo hi+lo.
// ---------------------------------------------------------------------------
__global__ __launch_bounds__(256) void pack_w4(
    const float* __restrict__ Wq, const float* __restrict__ Wk,
    const float* __restrict__ Wv, const float* __restrict__ Wo,
    short* __restrict__ WQh, short* __restrict__ WKh,
    short* __restrict__ WVh, short* __restrict__ WOh, short* __restrict__ WOl,
    long n)
{
  long i = ((long)blockIdx.x * 256 + threadIdx.x) * 4;
  if (i >= n) return;
  int which = blockIdx.y;
  if (which == 3) {
    fvec4 v = *(const fvec4*)&Wo[i];
    s16x4 h, l;
#pragma unroll
    for (int j = 0; j < 4; ++j) {
      short hb = f2bf(v[j]);
      h[j] = hb;
      l[j] = f2bf(v[j] - bf2f(hb));
    }
    *(s16x4*)&WOh[i] = h;
    *(s16x4*)&WOl[i] = l;
  } else {
    const float* src = which == 0 ? Wq : (which == 1 ? Wk : Wv);
    short* dst = which == 0 ? WQh : (which == 1 ? WKh : WVh);
    float sc = which == 0 ? QSC : 1.f;
    fvec4 v = *(const fvec4*)&src[i];
    s16x4 h;
#pragma unroll
    for (int j = 0; j < 4; ++j) h[j] = f2bf(v[j] * sc);
    *(s16x4*)&dst[i] = h;
  }
}

// pack_hi3: query/key/value -> bf16 hi planes, one launch (y selects).
__global__ __launch_bounds__(256) void pack_hi3(
    const float* __restrict__ q, const float* __restrict__ k,
    const float* __restrict__ v,
    short* __restrict__ xq, short* __restrict__ xk, short* __restrict__ xv,
    long n)
{
  long i = ((long)blockIdx.x * 256 + threadIdx.x) * 4;
  if (i >= n) return;
  const float* src = blockIdx.y == 0 ? q : (blockIdx.y == 1 ? k : v);
  short* dst = blockIdx.y == 0 ? xq : (blockIdx.y == 1 ? xk : xv);
  fvec4 x = *(const fvec4*)&src[i];
  s16x4 h;
#pragma unroll
  for (int j = 0; j < 4; ++j) h[j] = f2bf(x[j]);
  *(s16x4*)&dst[i] = h;
}

__global__ __launch_bounds__(256) void maskbias_k(
    const int* __restrict__ mask, float* __restrict__ mb, int n)
{
  int i = blockIdx.x * 256 + threadIdx.x;
  if (i < n) mb[i] = mask[i] ? 0.f : -1e30f;
}

// per-(b, 128-key-chunk) all-valid flags (64 chunks)
__global__ __launch_bounds__(64) void mask_flags(
    const int* __restrict__ mask, int* __restrict__ flg)
{
  int c = blockIdx.x;               // 0..63: b = c>>4, chunk = c&15
  int base = (c >> 4) * SEQ + (c & 15) * 128;
  int m0 = mask[base + threadIdx.x];
  int m1 = mask[base + 64 + threadIdx.x];
  unsigned long long bal = __ballot(m0 != 0 && m1 != 0);
  if (threadIdx.x == 0) flg[c] = (bal == ~0ull) ? 1 : 0;
}

// ---------------------------------------------------------------------------
// Fused QKV GEMM: one launch, blockIdx.z selects {Q,K,V}. bf16 MFMA,
// XOR-swizzled LDS, XCD-aware bijective block remap (512 blocks per slice,
// 512%8==0): XCD k owns 8 contiguous row-blocks x all col-blocks, so the
// A-panels (2MB) and the whole W (2MB) are L2-resident per XCD instead of
// every XCD refetching every A-panel via L3.
// z=0: QB=XBq@WQh^T+bq*QSC (bf16 [M,N]); z=1: KB; z=2: VT layout
// [(b*16+hd)*64+dd][SEQ] (fused V transpose).
// ---------------------------------------------------------------------------
__global__ __launch_bounds__(256) void gemm_qkv(
    const short* __restrict__ XBq, const short* __restrict__ XBk,
    const short* __restrict__ XBv,
    const short* __restrict__ WQh, const short* __restrict__ WKh,
    const short* __restrict__ WVh,
    const float* __restrict__ bq, const float* __restrict__ bk,
    const float* __restrict__ bv,
    short* __restrict__ QB, short* __restrict__ KB, short* __restrict__ VTo)
{
  __shared__ __align__(16) short sA[128*32];   // 8 KB
  __shared__ __align__(16) short sB[128*32];
  const int z = blockIdx.z;
  const short* A  = z == 0 ? XBq : (z == 1 ? XBk : XBv);
  const short* Bw = z == 0 ? WQh : (z == 1 ? WKh : WVh);
  const float* bias = z == 0 ? bq : (z == 1 ? bk : bv);
  short* Cb = z == 0 ? QB : (z == 1 ? KB : VTo);
  const float bscale = z == 0 ? QSC : 1.f;

  // XCD-aware bijective remap: flat F -> tile nb so XCD (F%8) gets a
  // contiguous nb range (rows 8k..8k+8, all cols).
  const int flat = blockIdx.y * 8 + blockIdx.x;           // 0..511
  const int nb = (flat & 7) * 64 + (flat >> 3);
  const int m0 = (nb >> 3) * 128, n0 = (nb & 7) * 128;

  const int t = threadIdx.x;
  const int ln = t & 15, quad = (t & 63) >> 4, w = t >> 6;
  const int wm = w >> 1, wn = w & 1;
  const int lrow = t >> 2;
  const int lko = (((t & 3) ^ ((t >> 3) & 3))) * 8;   // XOR-swizzled k-chunk
  const int fsw = ((ln >> 1) & 3);                     // frag-read swizzle key
  f32x4 acc[4][4];
#pragma unroll
  for (int i = 0; i < 4; ++i)
#pragma unroll
    for (int j = 0; j < 4; ++j) acc[i][j] = (f32x4){0.f,0.f,0.f,0.f};

  for (int k0 = 0; k0 < DIMN; k0 += 32) {
    __syncthreads();
#pragma unroll
    for (int u = 0; u < 2; ++u) {
      int row = u*64 + lrow;
      gld_lds16(A  + (size_t)(m0+row)*DIMN + k0 + lko, sA + u*2048 + t*8);
      gld_lds16(Bw + (size_t)(n0+row)*DIMN + k0 + lko, sB + u*2048 + t*8);
    }
    __syncthreads();
    bf16x8 af[4], bfr[4];
#pragma unroll
    for (int mt = 0; mt < 4; ++mt)
      af[mt] = *(bf16x8*)&sA[(wm*64 + mt*16 + ln)*32 + (quad ^ fsw)*8];
#pragma unroll
    for (int nt = 0; nt < 4; ++nt)
      bfr[nt] = *(bf16x8*)&sB[(wn*64 + nt*16 + ln)*32 + (quad ^ fsw)*8];
#pragma unroll
    for (int mt = 0; mt < 4; ++mt)
#pragma unroll
      for (int nt = 0; nt < 4; ++nt)
        acc[mt][nt] = __builtin_amdgcn_mfma_f32_16x16x32_bf16(af[mt], bfr[nt], acc[mt][nt], 0, 0, 0);
  }
#pragma unroll
  for (int nt = 0; nt < 4; ++nt) {
    int col = n0 + wn*64 + nt*16 + ln;
    float bv2 = bias[col] * bscale;
    if (z == 2) {
      int hd = col >> 6, dd = col & 63;
#pragma unroll
      for (int mt = 0; mt < 4; ++mt) {
        int sg = m0 + wm*64 + mt*16 + quad*4;
        int b = sg >> 11, s = sg & 2047;
        s16x4 h;
#pragma unroll
        for (int r = 0; r < 4; ++r) h[r] = f2bf(acc[mt][nt][r] + bv2);
        *(s16x4*)&Cb[((size_t)((b*16 + hd)*64 + dd))*SEQ + s] = h;
      }
    } else {
#pragma unroll
      for (int mt = 0; mt < 4; ++mt)
#pragma unroll
        for (int r = 0; r < 4; ++r) {
          int row = m0 + wm*64 + mt*16 + quad*4 + r;
          Cb[(size_t)row*DIMN + col] = f2bf(acc[mt][nt][r] + bv2);
        }
    }
  }
}

// ---------------------------------------------------------------------------
// 3-term split-bf16 GEMM (O-projection), XOR-swizzled LDS, XCD remap.
// ---------------------------------------------------------------------------
__global__ __launch_bounds__(256) void gemm_sp(
    const short* __restrict__ Ah, const short* __restrict__ Al,
    const short* __restrict__ Bh, const short* __restrict__ Bl,
    const float* __restrict__ bias, float bscale,
    float* __restrict__ C, int M, int N, int K)
{
  __shared__ __align__(16) short sA[2*128*32];   // 16 KB
  __shared__ __align__(16) short sB[2*128*32];
  const int t = threadIdx.x;
  const int ln = t & 15, quad = (t & 63) >> 4, w = t >> 6;
  const int wm = w >> 1, wn = w & 1;
  // XCD-aware bijective remap (512 blocks)
  const int flat = blockIdx.y * 8 + blockIdx.x;
  const int nb = (flat & 7) * 64 + (flat >> 3);
  const int m0 = (nb >> 3) * 128, n0 = (nb & 7) * 128;
  const int lrow = t >> 2;
  const int lko = (((t & 3) ^ ((t >> 3) & 3))) * 8;
  const int fsw = ((ln >> 1) & 3);
  f32x4 acc[4][4];
#pragma unroll
  for (int i = 0; i < 4; ++i)
#pragma unroll
    for (int j = 0; j < 4; ++j) acc[i][j] = (f32x4){0.f,0.f,0.f,0.f};

  for (int k0 = 0; k0 < K; k0 += 32) {
    __syncthreads();
#pragma unroll
    for (int u = 0; u < 2; ++u) {
      int row = u*64 + lrow;
      gld_lds16(Ah + (size_t)(m0+row)*K + k0 + lko, sA + u*2048 + t*8);
      gld_lds16(Al + (size_t)(m0+row)*K + k0 + lko, sA + 4096 + u*2048 + t*8);
      gld_lds16(Bh + (size_t)(n0+row)*K + k0 + lko, sB + u*2048 + t*8);
      gld_lds16(Bl + (size_t)(n0+row)*K + k0 + lko, sB + 4096 + u*2048 + t*8);
    }
    __syncthreads();
    bf16x8 ah[4], al[4], bh[4], bl[4];
#pragma unroll
    for (int mt = 0; mt < 4; ++mt) {
      int r = wm*64 + mt*16 + ln;
      ah[mt] = *(bf16x8*)&sA[r*32 + (quad ^ fsw)*8];
      al[mt] = *(bf16x8*)&sA[4096 + r*32 + (quad ^ fsw)*8];
    }
#pragma unroll
    for (int nt = 0; nt < 4; ++nt) {
      int r = wn*64 + nt*16 + ln;
      bh[nt] = *(bf16x8*)&sB[r*32 + (quad ^ fsw)*8];
      bl[nt] = *(bf16x8*)&sB[4096 + r*32 + (quad ^ fsw)*8];
    }
#pragma unroll
    for (int mt = 0; mt < 4; ++mt)
#pragma unroll
      for (int nt = 0; nt < 4; ++nt) {
        acc[mt][nt] = __builtin_amdgcn_mfma_f32_16x16x32_bf16(ah[mt], bh[nt], acc[mt][nt], 0, 0, 0);
        acc[mt][nt] = __builtin_amdgcn_mfma_f32_16x16x32_bf16(ah[mt], bl[nt], acc[mt][nt], 0, 0, 0);
        acc[mt][nt] = __builtin_amdgcn_mfma_f32_16x16x32_bf16(al[mt], bh[nt], acc[mt][nt], 0, 0, 0);
      }
  }
#pragma unroll
  for (int nt = 0; nt < 4; ++nt) {
    float bv = bias[n0 + wn*64 + nt*16 + ln] * bscale;
#pragma unroll
    for (int mt = 0; mt < 4; ++mt)
#pragma unroll
      for (int r = 0; r < 4; ++r)
        C[(size_t)(m0 + wm*64 + mt*16 + quad*4 + r)*N + (n0 + wn*64 + nt*16 + ln)] =
            acc[mt][nt][r] + bv;
  }
}

// ---------------------------------------------------------------------------
// Flash attention (round-1 attn_32, best measured: 139us): 32x32 MFMAs,
// in-register P via cvt_pk_bf16 + v_permlane32_swap_b32. Block = (b,h) x
// 128 q-rows, 4 waves. QK^T swapped: S^T[kc][q] = mfma(K, Q); PV as
// O^T[d][q] = mfma(V^T, P). LDS 32 KB single-buffer. Base-2 logits,
// defer-max THR=8.
// ---------------------------------------------------------------------------
__global__ __launch_bounds__(256, 3) void attn_32(
    const short* __restrict__ QB, const short* __restrict__ KB,
    const short* __restrict__ VT, const float* __restrict__ mb,
    const int* __restrict__ flg,
    short* __restrict__ CTXh, short* __restrict__ CTXl)
{
  __shared__ __align__(16) short lds[16384];   // 32 KB
  short* sK = lds;           // [128 kc][64 k], granule ^(kc&7); Q staged here first
  short* sV = lds + 8192;    // [64 d][128 kc], granule ^(d&15)

  const int t = threadIdx.x;
  const int l31 = t & 31, hi = (t >> 5) & 1, w = t >> 6;
  const int gb = blockIdx.x;
  const int chunk = gb >> 3, qt128 = chunk & 15, bh = ((chunk >> 4) << 3) + (gb & 7);
  const int b = bh >> 4, hd = bh & 15;

  // stage Q [128 q][64 k] into sK region, pull B-frags, then region is free
#pragma unroll
  for (int i = 0; i < 4; ++i) {
    int u = i*256 + t;
    int row = u >> 3, gr = (u & 7) ^ (row & 7);
    gld_lds16(QB + ((size_t)(b*SEQ + qt128*128 + row))*DIMN + hd*64 + gr*8,
              sK + u*8);
  }
  __syncthreads();
  const int q = w*32 + l31;
  bf16x8 qf[4];
#pragma unroll
  for (int ks = 0; ks < 4; ++ks)
    qf[ks] = *(bf16x8*)&sK[q*64 + ((ks*2 + hi) ^ (q & 7))*8];

  f32x16 o_acc[2] = {};          // O^T: col = own q (l31), rows d
  float m_run = -1e30f, l_run = 0.f;

  for (int kt = 0; kt < SEQ/128; ++kt) {
    __syncthreads();             // all waves done with prev sK/sV
#pragma unroll
    for (int i = 0; i < 4; ++i) {
      int u = i*256 + t;
      { int row = u >> 3, gr = (u & 7) ^ (row & 7);
        gld_lds16(KB + ((size_t)(b*SEQ + kt*128 + row))*DIMN + hd*64 + gr*8,
                  sK + u*8); }
      { int d = u >> 4, gr = (u & 15) ^ (d & 15);
        gld_lds16(VT + ((size_t)(bh*64 + d))*SEQ + kt*128 + gr*8,
                  sV + u*8); }
    }
    __syncthreads();

    // S^T[kc][q]: 4 kc-tiles of 32. Lane holds col q=l31,
    // rows kc = mt*32 + (r&3) + 8*(r>>2) + 4*hi.
    f32x16 sacc[4] = {};
#pragma unroll
    for (int ks = 0; ks < 4; ++ks)
#pragma unroll
      for (int mt = 0; mt < 4; ++mt) {
        int kc = mt*32 + l31;
        bf16x8 kf = *(bf16x8*)&sK[kc*64 + ((ks*2 + hi) ^ (kc & 7))*8];
        sacc[mt] = __builtin_amdgcn_mfma_f32_32x32x16_bf16(kf, qf[ks], sacc[mt], 0, 0, 0);
      }

    if (!flg[b*16 + kt]) {       // mask slow path (bench: all-valid fast path)
#pragma unroll
      for (int mt = 0; mt < 4; ++mt)
#pragma unroll
        for (int r = 0; r < 16; ++r)
          sacc[mt][r] += mb[b*SEQ + kt*128 + mt*32 + (r&3) + 8*(r>>2) + 4*hi];
    }

    // online softmax: lane owns q = l31; other 64 kc values live in lane^32
    float tmax = -1e30f;
#pragma unroll
    for (int mt = 0; mt < 4; ++mt)
#pragma unroll
      for (int r = 0; r < 16; ++r) tmax = fmaxf(tmax, sacc[mt][r]);
    tmax = fmaxf(tmax, __shfl_xor(tmax, 32));

    if (!__all(tmax <= m_run + 8.f)) {   // defer-max: P bounded by 2^8
      float mnew = fmaxf(m_run, tmax);
      float alpha = exp2f(m_run - mnew);
      l_run *= alpha;
#pragma unroll
      for (int dt = 0; dt < 2; ++dt)
#pragma unroll
        for (int r = 0; r < 16; ++r) o_acc[dt][r] *= alpha;
      m_run = mnew;
    }

    float rs = 0.f;
#pragma unroll
    for (int mt = 0; mt < 4; ++mt)
#pragma unroll
      for (int r = 0; r < 16; ++r) {
        float p = exp2f(sacc[mt][r] - m_run);
        sacc[mt][r] = p;
        rs += p;
      }
    rs += __shfl_xor(rs, 32);
    l_run += rs;

    // P -> bf16 B-frags in-register; O^T += mfma(V^T-frag, P-frag).
#pragma unroll
    for (int mt = 0; mt < 4; ++mt) {
      unsigned wv[8];
#pragma unroll
      for (int i = 0; i < 8; ++i) {
        float plo = sacc[mt][2*i], phi = sacc[mt][2*i+1];
        asm("v_cvt_pk_bf16_f32 %0, %1, %2" : "=v"(wv[i]) : "v"(plo), "v"(phi));
      }
#pragma unroll
      for (int h = 0; h < 2; ++h) {
        unsigned f0 = wv[h*4+0], f1 = wv[h*4+1], f2 = wv[h*4+2], f3 = wv[h*4+3];
        asm volatile("v_permlane32_swap_b32 %0, %1" : "+v"(f0), "+v"(f2));
        asm volatile("v_permlane32_swap_b32 %0, %1" : "+v"(f1), "+v"(f3));
        union { unsigned u[4]; bf16x8 v; } pu;
        pu.u[0] = f0; pu.u[1] = f1; pu.u[2] = f2; pu.u[3] = f3;
        const int kcs = mt*2 + h;      // 16-wide kc step, 0..7
#pragma unroll
        for (int dt = 0; dt < 2; ++dt) {
          int d = dt*32 + l31;
          bf16x8 vf = *(bf16x8*)&sV[d*128 + ((kcs*2 + hi) ^ (d & 15))*8];
          o_acc[dt] = __builtin_amdgcn_mfma_f32_32x32x16_bf16(vf, pu.v, o_acc[dt], 0, 0, 0);
        }
      }
    }
  }

  // epilogue: lane holds O^T col q (its own), rows d = dt*32 + r2 + 8*rg + 4*hi
  float invl = (l_run > 0.f) ? 1.f / l_run : 0.f;
  const size_t rowbase = (size_t)(b*SEQ + qt128*128 + q)*DIMN + hd*64;
#pragma unroll
  for (int dt = 0; dt < 2; ++dt)
#pragma unroll
    for (int rg = 0; rg < 4; ++rg) {
      s16x4 hq, lq;
#pragma unroll
      for (int r2 = 0; r2 < 4; ++r2) {
        float val = o_acc[dt][rg*4 + r2] * invl;
        short hb = f2bf(val);
        hq[r2] = hb;
        lq[r2] = f2bf(val - bf2f(hb));
      }
      size_t idx = rowbase + dt*32 + rg*8 + hi*4;
      *(s16x4*)&CTXh[idx] = hq;
      *(s16x4*)&CTXl[idx] = lq;
    }
}

// ===========================================================================
// Fallback fp32 path for small ws_size.
// ===========================================================================
__global__ __launch_bounds__(256) void gemm_bt(
    const float* __restrict__ X, const float* __restrict__ W,
    const float* __restrict__ bias, float* __restrict__ C,
    int M, int N, int K)
{
  __shared__ __align__(16) float Xs[16][68];
  __shared__ __align__(16) float Ws[16][68];
  const int t  = threadIdx.x;
  const int tx = t & 15, ty = t >> 4;
  const int m0 = blockIdx.y << 6, n0 = blockIdx.x << 6;
  const int ldr = t >> 2;
  const int lk  = (t & 3) << 2;
  float acc[4][4] = {{0.f}};
  const float* Xp = X + (size_t)(m0 + ldr) * K + lk;
  const float* Wp = W + (size_t)(n0 + ldr) * K + lk;
  for (int k0 = 0; k0 < K; k0 += 16) {
    float4 xa = *(const float4*)(Xp + k0);
    float4 wa = *(const float4*)(Wp + k0);
    Xs[lk+0][ldr]=xa.x; Xs[lk+1][ldr]=xa.y; Xs[lk+2][ldr]=xa.z; Xs[lk+3][ldr]=xa.w;
    Ws[lk+0][ldr]=wa.x; Ws[lk+1][ldr]=wa.y; Ws[lk+2][ldr]=wa.z; Ws[lk+3][ldr]=wa.w;
    __syncthreads();
#pragma unroll
    for (int kk = 0; kk < 16; ++kk) {
      float4 a4 = *(const float4*)&Xs[kk][ty<<2];
      float4 b4 = *(const float4*)&Ws[kk][tx<<2];
      float av[4] = {a4.x, a4.y, a4.z, a4.w};
      float bv[4] = {b4.x, b4.y, b4.z, b4.w};
#pragma unroll
      for (int i = 0; i < 4; ++i)
#pragma unroll
        for (int j = 0; j < 4; ++j)
          acc[i][j] = fmaf(av[i], bv[j], acc[i][j]);
    }
    __syncthreads();
  }
  float4 bb4 = *(const float4*)&bias[n0 + (tx<<2)];
  const float bv[4] = {bb4.x, bb4.y, bb4.z, bb4.w};
#pragma unroll
  for (int i = 0; i < 4; ++i) {
    float4 o;
    o.x = acc[i][0]+bv[0]; o.y = acc[i][1]+bv[1];
    o.z = acc[i][2]+bv[2]; o.w = acc[i][3]+bv[3];
    *(float4*)&C[(size_t)(m0 + (ty<<2) + i) * N + n0 + (tx<<2)] = o;
  }
}

__global__ __launch_bounds__(256) void attn_fwd(
    const float* __restrict__ Q, const float* __restrict__ Kbuf,
    const float* __restrict__ Vbuf, const int* __restrict__ mask,
    float* __restrict__ CTX)
{
  __shared__ __align__(16) float Qs[64][68];
  __shared__ __align__(16) float KPs[64][68];
  __shared__ __align__(16) float Vs[64][68];
  const int t  = threadIdx.x;
  const int tx = t & 15, ty = t >> 4;
  const int qt = blockIdx.x;
  const int bh = blockIdx.y;
  const int b  = bh >> 4, h = bh & 15;
  const int ldr = t >> 2;
  const int lcb = (t & 3) << 2;
  const float* Qp = Q + (size_t)(b*SEQ + (qt<<6)) * DIMN + h*DHEAD;
#pragma unroll
  for (int u = 0; u < 4; ++u) {
    int kb = lcb + (u<<4);
    float4 q4 = *(const float4*)(Qp + (size_t)ldr*DIMN + kb);
    Qs[kb+0][ldr]=q4.x; Qs[kb+1][ldr]=q4.y; Qs[kb+2][ldr]=q4.z; Qs[kb+3][ldr]=q4.w;
  }
  float mrow[4], lsum[4], o[4][4];
#pragma unroll
  for (int i = 0; i < 4; ++i) {
    mrow[i] = -1e30f; lsum[i] = 0.f;
#pragma unroll
    for (int j = 0; j < 4; ++j) o[i][j] = 0.f;
  }
  const int qrow0 = ty << 2;
  const int col0  = tx << 2;
  for (int kt = 0; kt < SEQ/64; ++kt) {
    __syncthreads();
    const float* Kp = Kbuf + (size_t)(b*SEQ + (kt<<6)) * DIMN + h*DHEAD;
    const float* Vp = Vbuf + (size_t)(b*SEQ + (kt<<6)) * DIMN + h*DHEAD;
#pragma unroll
    for (int u = 0; u < 4; ++u) {
      int kb = lcb + (u<<4);
      float4 k4 = *(const float4*)(Kp + (size_t)ldr*DIMN + kb);
      KPs[kb+0][ldr]=k4.x; KPs[kb+1][ldr]=k4.y; KPs[kb+2][ldr]=k4.z; KPs[kb+3][ldr]=k4.w;
      float4 v4 = *(const float4*)(Vp + (size_t)ldr*DIMN + kb);
      *(float4*)&Vs[ldr][kb] = v4;
    }
    __syncthreads();
    float s[4][4] = {{0.f}};
#pragma unroll 8
    for (int kk = 0; kk < 64; ++kk) {
      float4 a4 = *(const float4*)&Qs[kk][qrow0];
      float4 b4 = *(const float4*)&KPs[kk][col0];
      float av[4] = {a4.x, a4.y, a4.z, a4.w};
      float bv[4] = {b4.x, b4.y, b4.z, b4.w};
#pragma unroll
      for (int i = 0; i < 4; ++i)
#pragma unroll
        for (int j = 0; j < 4; ++j)
          s[i][j] = fmaf(av[i], bv[j], s[i][j]);
    }
    int mk[4];
#pragma unroll
    for (int j = 0; j < 4; ++j) mk[j] = mask[b*SEQ + (kt<<6) + col0 + j];
    float p[4][4];
#pragma unroll
    for (int i = 0; i < 4; ++i) {
#pragma unroll
      for (int j = 0; j < 4; ++j)
        s[i][j] = mk[j] ? s[i][j]*0.125f : -1e30f;
      float tm = fmaxf(fmaxf(s[i][0], s[i][1]), fmaxf(s[i][2], s[i][3]));
#pragma unroll
      for (int off = 8; off >= 1; off >>= 1)
        tm = fmaxf(tm, __shfl_xor(tm, off, 64));
      float mnew  = fmaxf(mrow[i], tm);
      float aa = __expf(mrow[i] - mnew);
      mrow[i] = mnew;
      float rsum = 0.f;
#pragma unroll
      for (int j = 0; j < 4; ++j) {
        float pv = __expf(s[i][j] - mnew);
        p[i][j] = pv; rsum += pv;
      }
#pragma unroll
      for (int off = 8; off >= 1; off >>= 1)
        rsum += __shfl_xor(rsum, off, 64);
      lsum[i] = lsum[i]*aa + rsum;
#pragma unroll
      for (int j = 0; j < 4; ++j) o[i][j] *= aa;
    }
    __syncthreads();
#pragma unroll
    for (int i = 0; i < 4; ++i)
#pragma unroll
      for (int j = 0; j < 4; ++j)
        KPs[col0 + j][qrow0 + i] = p[i][j];
    __syncthreads();
#pragma unroll 8
    for (int kk = 0; kk < 64; ++kk) {
      float4 a4 = *(const float4*)&KPs[kk][qrow0];
      float4 v4 = *(const float4*)&Vs[kk][col0];
      float av[4] = {a4.x, a4.y, a4.z, a4.w};
      float vv[4] = {v4.x, v4.y, v4.z, v4.w};
#pragma unroll
      for (int i = 0; i < 4; ++i)
#pragma unroll
        for (int j = 0; j < 4; ++j)
          o[i][j] = fmaf(av[i], vv[j], o[i][j]);
    }
  }
  float* Cp = CTX + (size_t)(b*SEQ + (qt<<6)) * DIMN + h*DHEAD;
#pragma unroll
  for (int i = 0; i < 4; ++i) {
    float inv = lsum[i] > 0.f ? 1.0f/lsum[i] : 0.f;
    float4 ov;
    ov.x = o[i][0]*inv; ov.y = o[i][1]*inv;
    ov.z = o[i][2]*inv; ov.w = o[i][3]*inv;
    *(float4*)(Cp + (size_t)(qrow0 + i)*DIMN + col0) = ov;
  }
}

// ---------------------------------------------------------------------------
extern "C" void kernel_launch(void* const* d_in, const int* in_sizes, int n_in,
                              void* d_out, int out_size, void* d_ws, size_t ws_size,
                              hipStream_t stream)
{
  const float* query = (const float*)d_in[0];
  const float* key   = (const float*)d_in[1];
  const float* value = (const float*)d_in[2];
  const int*   mask  = (const int*)d_in[3];
  const float* Wq = (const float*)d_in[4];
  const float* bq = (const float*)d_in[5];
  const float* Wk = (const float*)d_in[6];
  const float* bk = (const float*)d_in[7];
  const float* Wv = (const float*)d_in[8];
  const float* bv = (const float*)d_in[9];
  const float* Wo = (const float*)d_in[10];
  const float* bo = (const float*)d_in[11];
  float* out = (float*)d_out;

  const size_t E  = (size_t)MROWS * DIMN;   // 8,388,608
  const size_t WE = (size_t)DIMN * DIMN;    // 1,048,576

  // ws layout (bytes)
  const size_t o_XB   = 5*WE*2;                 // weights: 10 MB
  const size_t o_QB   = o_XB   + 3*E*2;         // XBq,XBk,XBv: 48 MB
  const size_t o_KB   = o_QB   + E*2;
  const size_t o_VT   = o_KB   + E*2;
  const size_t o_CTXh = o_VT   + E*2;
  const size_t o_CTXl = o_CTXh + E*2;
  const size_t o_MB   = o_CTXl + E*2;
  const size_t o_FLG  = o_MB   + MROWS*4;
  const size_t NEED   = o_FLG  + 64*4;          // ~138 MB

  if (ws_size < NEED) {
    const size_t n = E;
    float* Qb = (float*)d_ws;
    float* Kb = Qb + n;
    float* Vb = Kb + n;
    float* Cb = Vb + n;
    dim3 gg(DIMN/64, MROWS/64), blk(256);
    hipLaunchKernelGGL(gemm_bt, gg, blk, 0, stream, query, Wq, bq, Qb, MROWS, DIMN, DIMN);
    hipLaunchKernelGGL(gemm_bt, gg, blk, 0, stream, key,   Wk, bk, Kb, MROWS, DIMN, DIMN);
    hipLaunchKernelGGL(gemm_bt, gg, blk, 0, stream, value, Wv, bv, Vb, MROWS, DIMN, DIMN);
    dim3 ga(SEQ/64, BSZ*NHEAD);
    hipLaunchKernelGGL(attn_fwd, ga, blk, 0, stream, Qb, Kb, Vb, mask, Cb);
    hipLaunchKernelGGL(gemm_bt, gg, blk, 0, stream, Cb, Wo, bo, out, MROWS, DIMN, DIMN);
    return;
  }

  char* Wp = (char*)d_ws;
  short* WQh = (short*)Wp;
  short* WKh = WQh + WE;
  short* WVh = WQh + 2*WE;
  short* WOh = WQh + 3*WE;
  short* WOl = WQh + 4*WE;
  short* XBq  = (short*)(Wp + o_XB);
  short* XBk  = XBq + E;
  short* XBv  = XBk + E;
  short* QB   = (short*)(Wp + o_QB);
  short* KB   = (short*)(Wp + o_KB);
  short* VT   = (short*)(Wp + o_VT);
  short* CTXh = (short*)(Wp + o_CTXh);
  short* CTXl = (short*)(Wp + o_CTXl);
  float* MB   = (float*)(Wp + o_MB);
  int*   FLG  = (int*)(Wp + o_FLG);

  dim3 blk(256);
  dim3 gW(WE/1024, 4), gX(E/1024, 3);
  dim3 gqkv(DIMN/128, MROWS/128, 3);  // (8, 64, 3)
  dim3 gg(DIMN/128, MROWS/128);       // (8, 64)
  dim3 gat(BSZ*NHEAD*SEQ/128);        // 1024

  hipLaunchKernelGGL(pack_w4, gW, blk, 0, stream, Wq, Wk, Wv, Wo,
                     WQh, WKh, WVh, WOh, WOl, (long)WE);
  hipLaunchKernelGGL(maskbias_k, dim3(MROWS/256), blk, 0, stream, mask, MB, MROWS);
  hipLaunchKernelGGL(mask_flags, dim3(64), dim3(64), 0, stream, mask, FLG);
  hipLaunchKernelGGL(pack_hi3, gX, blk, 0, stream, query, key, value,
                     XBq, XBk, XBv, (long)E);

  hipLaunchKernelGGL(gemm_qkv, gqkv, blk, 0, stream,
                     XBq, XBk, XBv, WQh, WKh, WVh, bq, bk, bv, QB, KB, VT);

  hipLaunchKernelGGL(attn_32, gat, blk, 0, stream, QB, KB, VT, MB, FLG, CTXh, CTXl);

  hipLaunchKernelGGL(gemm_sp, gg, blk, 0, stream, CTXh, CTXl, WOh, WOl, bo, 1.f,
                     out, MROWS, DIMN, DIMN);
}

// Round 7
// 399.564 us; speedup vs baseline: 1.2618x; 1.0451x over previous
//
#include <hip/hip_runtime.h>
#include <hip/hip_bf16.h>
#include <math.h>

#define BSZ 4
#define SEQ 2048
#define DIMN 1024
#define NHEAD 16
#define DHEAD 64
#define MROWS (BSZ*SEQ)   // 8192

typedef __bf16 bf16x8 __attribute__((ext_vector_type(8)));
typedef float  f32x4  __attribute__((ext_vector_type(4)));
typedef float  f32x16 __attribute__((ext_vector_type(16)));
typedef float  fvec4  __attribute__((ext_vector_type(4)));
typedef short  s16x4  __attribute__((ext_vector_type(4)));
typedef short  s16x8  __attribute__((ext_vector_type(8)));

__device__ __forceinline__ short f2bf(float v) {
  __hip_bfloat16 b = __float2bfloat16(v);   // RNE
  return *reinterpret_cast<short*>(&b);
}
__device__ __forceinline__ float bf2f(short s) {
  __hip_bfloat16 b = *reinterpret_cast<__hip_bfloat16*>(&s);
  return __bfloat162float(b);
}

__device__ __forceinline__ void gld_lds16(const void* g, void* l) {
  __builtin_amdgcn_global_load_lds((const __attribute__((address_space(1))) void*)g,
                                   (__attribute__((address_space(3))) void*)l, 16, 0, 0);
}

// 0.125 (1/sqrt(DH)) * log2(e): folds softmax base-2 conversion into Wq/bq.
#define QSC 0.18033688011112042f

// ---------------------------------------------------------------------------
// pack_w4: all four weight packs in one launch. y=0 Wq*QSC hi, 1 Wk hi,
// 2 Wv hi, 3 Wo hi+lo.
// ---------------------------------------------------------------------------
__global__ __launch_bounds__(256) void pack_w4(
    const float* __restrict__ Wq, const float* __restrict__ Wk,
    const float* __restrict__ Wv, const float* __restrict__ Wo,
    short* __restrict__ WQh, short* __restrict__ WKh,
    short* __restrict__ WVh, short* __restrict__ WOh, short* __restrict__ WOl,
    long n)
{
  long i = ((long)blockIdx.x * 256 + threadIdx.x) * 4;
  if (i >= n) return;
  int which = blockIdx.y;
  if (which == 3) {
    fvec4 v = *(const fvec4*)&Wo[i];
    s16x4 h, l;
#pragma unroll
    for (int j = 0; j < 4; ++j) {
      short hb = f2bf(v[j]);
      h[j] = hb;
      l[j] = f2bf(v[j] - bf2f(hb));
    }
    *(s16x4*)&WOh[i] = h;
    *(s16x4*)&WOl[i] = l;
  } else {
    const float* src = which == 0 ? Wq : (which == 1 ? Wk : Wv);
    short* dst = which == 0 ? WQh : (which == 1 ? WKh : WVh);
    float sc = which == 0 ? QSC : 1.f;
    fvec4 v = *(const fvec4*)&src[i];
    s16x4 h;
#pragma unroll
    for (int j = 0; j < 4; ++j) h[j] = f2bf(v[j] * sc);
    *(s16x4*)&dst[i] = h;
  }
}

// pack_hi3: query/key/value -> bf16 hi planes, one launch (y selects).
__global__ __launch_bounds__(256) void pack_hi3(
    const float* __restrict__ q, const float* __restrict__ k,
    const float* __restrict__ v,
    short* __restrict__ xq, short* __restrict__ xk, short* __restrict__ xv,
    long n)
{
  long i = ((long)blockIdx.x * 256 + threadIdx.x) * 4;
  if (i >= n) return;
  const float* src = blockIdx.y == 0 ? q : (blockIdx.y == 1 ? k : v);
  short* dst = blockIdx.y == 0 ? xq : (blockIdx.y == 1 ? xk : xv);
  fvec4 x = *(const fvec4*)&src[i];
  s16x4 h;
#pragma unroll
  for (int j = 0; j < 4; ++j) h[j] = f2bf(x[j]);
  *(s16x4*)&dst[i] = h;
}

__global__ __launch_bounds__(256) void maskbias_k(
    const int* __restrict__ mask, float* __restrict__ mb, int n)
{
  int i = blockIdx.x * 256 + threadIdx.x;
  if (i < n) mb[i] = mask[i] ? 0.f : -1e30f;
}

// per-(b, 128-key-chunk) all-valid flags (64 chunks)
__global__ __launch_bounds__(64) void mask_flags(
    const int* __restrict__ mask, int* __restrict__ flg)
{
  int c = blockIdx.x;               // 0..63: b = c>>4, chunk = c&15
  int base = (c >> 4) * SEQ + (c & 15) * 128;
  int m0 = mask[base + threadIdx.x];
  int m1 = mask[base + 64 + threadIdx.x];
  unsigned long long bal = __ballot(m0 != 0 && m1 != 0);
  if (threadIdx.x == 0) flg[c] = (bal == ~0ull) ? 1 : 0;
}

// ---------------------------------------------------------------------------
// Fused QKV GEMM v2: 32x32x16 MFMA (2495 vs 2075 TF ceiling, ~17% fewer
// matrix-pipe cycles), BK=64 (halves barrier drains: 16 K-iters), attn-style
// granule swizzle [row][64] g^(row&7) (both-sides involution, proven in
// attn_32). XCD-aware bijective block remap. blockIdx.z selects {Q,K,V}.
// z=2 writes VT layout [(b*16+hd)*64+dd][SEQ] (fused V transpose).
// ---------------------------------------------------------------------------
__global__ __launch_bounds__(256) void gemm_qkv(
    const short* __restrict__ XBq, const short* __restrict__ XBk,
    const short* __restrict__ XBv,
    const short* __restrict__ WQh, const short* __restrict__ WKh,
    const short* __restrict__ WVh,
    const float* __restrict__ bq, const float* __restrict__ bk,
    const float* __restrict__ bv,
    short* __restrict__ QB, short* __restrict__ KB, short* __restrict__ VTo)
{
  __shared__ __align__(16) short sA[128*64];   // 16 KB
  __shared__ __align__(16) short sB[128*64];   // 16 KB
  const int z = blockIdx.z;
  const short* A  = z == 0 ? XBq : (z == 1 ? XBk : XBv);
  const short* Bw = z == 0 ? WQh : (z == 1 ? WKh : WVh);
  const float* bias = z == 0 ? bq : (z == 1 ? bk : bv);
  short* Cb = z == 0 ? QB : (z == 1 ? KB : VTo);
  const float bscale = z == 0 ? QSC : 1.f;

  // XCD-aware bijective remap (512 blocks/slice, 512%8==0)
  const int flat = blockIdx.y * 8 + blockIdx.x;           // 0..511
  const int nb = (flat & 7) * 64 + (flat >> 3);
  const int m0 = (nb >> 3) * 128, n0 = (nb & 7) * 128;

  const int t = threadIdx.x;
  const int l31 = t & 31, hi = (t >> 5) & 1, w = t >> 6;
  const int wm = w >> 1, wn = w & 1;
  // staging decomposition: unit u = i*256+t -> row = i*32 + (t>>3), c = t&7
  const int srow7 = (t >> 3) & 7;
  const int sg = (t & 7) ^ srow7;            // swizzled granule (pre-swizzled src)
  // hoisted frag read offsets: row r, k-slice ks: r*64 + ((ks*2+hi)^(r&7))*8,
  // r&7 == l31&7 for all tile rows.
  int offF[4];
#pragma unroll
  for (int ks = 0; ks < 4; ++ks)
    offF[ks] = l31*64 + ((ks*2 + hi) ^ (l31 & 7))*8;

  f32x16 acc[2][2] = {};

  for (int k0 = 0; k0 < DIMN; k0 += 64) {
    __syncthreads();
#pragma unroll
    for (int i = 0; i < 4; ++i) {
      int row = i*32 + (t >> 3);
      gld_lds16(A  + (size_t)(m0+row)*DIMN + k0 + sg*8, sA + (i*256 + t)*8);
      gld_lds16(Bw + (size_t)(n0+row)*DIMN + k0 + sg*8, sB + (i*256 + t)*8);
    }
    __syncthreads();
#pragma unroll
    for (int ks = 0; ks < 4; ++ks) {
      bf16x8 af0 = *(const bf16x8*)&sA[wm*4096 + offF[ks]];
      bf16x8 af1 = *(const bf16x8*)&sA[wm*4096 + 2048 + offF[ks]];
      bf16x8 bf0 = *(const bf16x8*)&sB[wn*4096 + offF[ks]];
      bf16x8 bf1 = *(const bf16x8*)&sB[wn*4096 + 2048 + offF[ks]];
      acc[0][0] = __builtin_amdgcn_mfma_f32_32x32x16_bf16(af0, bf0, acc[0][0], 0, 0, 0);
      acc[0][1] = __builtin_amdgcn_mfma_f32_32x32x16_bf16(af0, bf1, acc[0][1], 0, 0, 0);
      acc[1][0] = __builtin_amdgcn_mfma_f32_32x32x16_bf16(af1, bf0, acc[1][0], 0, 0, 0);
      acc[1][1] = __builtin_amdgcn_mfma_f32_32x32x16_bf16(af1, bf1, acc[1][1], 0, 0, 0);
    }
  }

  // epilogue: D col = n0+wn*64+nt*32+l31; rows = m0+wm*64+mt*32+rg*8+hi*4+r2
#pragma unroll
  for (int nt = 0; nt < 2; ++nt) {
    int col = n0 + wn*64 + nt*32 + l31;
    float bv2 = bias[col] * bscale;
    if (z == 2) {
      int hd = col >> 6, dd = col & 63;
#pragma unroll
      for (int mt = 0; mt < 2; ++mt)
#pragma unroll
        for (int rg = 0; rg < 4; ++rg) {
          int sgr = m0 + wm*64 + mt*32 + rg*8 + hi*4;
          int b = sgr >> 11, s = sgr & 2047;
          s16x4 h;
#pragma unroll
          for (int r2 = 0; r2 < 4; ++r2) h[r2] = f2bf(acc[mt][nt][rg*4+r2] + bv2);
          *(s16x4*)&Cb[((size_t)((b*16 + hd)*64 + dd))*SEQ + s] = h;
        }
    } else {
#pragma unroll
      for (int mt = 0; mt < 2; ++mt)
#pragma unroll
        for (int rg = 0; rg < 4; ++rg)
#pragma unroll
          for (int r2 = 0; r2 < 4; ++r2) {
            int row = m0 + wm*64 + mt*32 + rg*8 + hi*4 + r2;
            Cb[(size_t)row*DIMN + col] = f2bf(acc[mt][nt][rg*4+r2] + bv2);
          }
    }
  }
}

// ---------------------------------------------------------------------------
// 3-term split-bf16 GEMM v2 (O-projection): 32x32x16 MFMA, BK=64, attn-style
// granule swizzle, XCD remap. LDS 64 KB (4 matrices x 16 KB).
// ---------------------------------------------------------------------------
__global__ __launch_bounds__(256) void gemm_sp(
    const short* __restrict__ Ah, const short* __restrict__ Al,
    const short* __restrict__ Bh, const short* __restrict__ Bl,
    const float* __restrict__ bias, float bscale,
    float* __restrict__ C, int M, int N, int K)
{
  __shared__ __align__(16) short sA[2*128*64];   // Ah | Al : 32 KB
  __shared__ __align__(16) short sB[2*128*64];   // Bh | Bl : 32 KB
  const int t = threadIdx.x;
  const int l31 = t & 31, hi = (t >> 5) & 1, w = t >> 6;
  const int wm = w >> 1, wn = w & 1;
  // XCD-aware bijective remap (512 blocks)
  const int flat = blockIdx.y * 8 + blockIdx.x;
  const int nb = (flat & 7) * 64 + (flat >> 3);
  const int m0 = (nb >> 3) * 128, n0 = (nb & 7) * 128;
  const int sg = (t & 7) ^ ((t >> 3) & 7);
  int offF[4];
#pragma unroll
  for (int ks = 0; ks < 4; ++ks)
    offF[ks] = l31*64 + ((ks*2 + hi) ^ (l31 & 7))*8;

  f32x16 acc[2][2] = {};

  for (int k0 = 0; k0 < K; k0 += 64) {
    __syncthreads();
#pragma unroll
    for (int i = 0; i < 4; ++i) {
      int row = i*32 + (t >> 3);
      int u8 = (i*256 + t)*8;
      gld_lds16(Ah + (size_t)(m0+row)*K + k0 + sg*8, sA + u8);
      gld_lds16(Al + (size_t)(m0+row)*K + k0 + sg*8, sA + 8192 + u8);
      gld_lds16(Bh + (size_t)(n0+row)*K + k0 + sg*8, sB + u8);
      gld_lds16(Bl + (size_t)(n0+row)*K + k0 + sg*8, sB + 8192 + u8);
    }
    __syncthreads();
#pragma unroll
    for (int ks = 0; ks < 4; ++ks) {
      bf16x8 ah0 = *(const bf16x8*)&sA[wm*4096 + offF[ks]];
      bf16x8 ah1 = *(const bf16x8*)&sA[wm*4096 + 2048 + offF[ks]];
      bf16x8 al0 = *(const bf16x8*)&sA[8192 + wm*4096 + offF[ks]];
      bf16x8 al1 = *(const bf16x8*)&sA[8192 + wm*4096 + 2048 + offF[ks]];
      bf16x8 bh0 = *(const bf16x8*)&sB[wn*4096 + offF[ks]];
      bf16x8 bh1 = *(const bf16x8*)&sB[wn*4096 + 2048 + offF[ks]];
      bf16x8 bl0 = *(const bf16x8*)&sB[8192 + wn*4096 + offF[ks]];
      bf16x8 bl1 = *(const bf16x8*)&sB[8192 + wn*4096 + 2048 + offF[ks]];
      acc[0][0] = __builtin_amdgcn_mfma_f32_32x32x16_bf16(ah0, bh0, acc[0][0], 0, 0, 0);
      acc[0][0] = __builtin_amdgcn_mfma_f32_32x32x16_bf16(ah0, bl0, acc[0][0], 0, 0, 0);
      acc[0][0] = __builtin_amdgcn_mfma_f32_32x32x16_bf16(al0, bh0, acc[0][0], 0, 0, 0);
      acc[0][1] = __builtin_amdgcn_mfma_f32_32x32x16_bf16(ah0, bh1, acc[0][1], 0, 0, 0);
      acc[0][1] = __builtin_amdgcn_mfma_f32_32x32x16_bf16(ah0, bl1, acc[0][1], 0, 0, 0);
      acc[0][1] = __builtin_amdgcn_mfma_f32_32x32x16_bf16(al0, bh1, acc[0][1], 0, 0, 0);
      acc[1][0] = __builtin_amdgcn_mfma_f32_32x32x16_bf16(ah1, bh0, acc[1][0], 0, 0, 0);
      acc[1][0] = __builtin_amdgcn_mfma_f32_32x32x16_bf16(ah1, bl0, acc[1][0], 0, 0, 0);
      acc[1][0] = __builtin_amdgcn_mfma_f32_32x32x16_bf16(al1, bh0, acc[1][0], 0, 0, 0);
      acc[1][1] = __builtin_amdgcn_mfma_f32_32x32x16_bf16(ah1, bh1, acc[1][1], 0, 0, 0);
      acc[1][1] = __builtin_amdgcn_mfma_f32_32x32x16_bf16(ah1, bl1, acc[1][1], 0, 0, 0);
      acc[1][1] = __builtin_amdgcn_mfma_f32_32x32x16_bf16(al1, bh1, acc[1][1], 0, 0, 0);
    }
  }

#pragma unroll
  for (int nt = 0; nt < 2; ++nt) {
    int col = n0 + wn*64 + nt*32 + l31;
    float bv = bias[col] * bscale;
#pragma unroll
    for (int mt = 0; mt < 2; ++mt)
#pragma unroll
      for (int rg = 0; rg < 4; ++rg)
#pragma unroll
        for (int r2 = 0; r2 < 4; ++r2) {
          int row = m0 + wm*64 + mt*32 + rg*8 + hi*4 + r2;
          C[(size_t)row*N + col] = acc[mt][nt][rg*4+r2] + bv;
        }
  }
}

// ---------------------------------------------------------------------------
// Flash attention (round-1 attn_32, best measured: 139us): 32x32 MFMAs,
// in-register P via cvt_pk_bf16 + v_permlane32_swap_b32. Block = (b,h) x
// 128 q-rows, 4 waves. QK^T swapped: S^T[kc][q] = mfma(K, Q); PV as
// O^T[d][q] = mfma(V^T, P). LDS 32 KB single-buffer. Base-2 logits,
// defer-max THR=8.
// ---------------------------------------------------------------------------
__global__ __launch_bounds__(256, 3) void attn_32(
    const short* __restrict__ QB, const short* __restrict__ KB,
    const short* __restrict__ VT, const float* __restrict__ mb,
    const int* __restrict__ flg,
    short* __restrict__ CTXh, short* __restrict__ CTXl)
{
  __shared__ __align__(16) short lds[16384];   // 32 KB
  short* sK = lds;           // [128 kc][64 k], granule ^(kc&7); Q staged here first
  short* sV = lds + 8192;    // [64 d][128 kc], granule ^(d&15)

  const int t = threadIdx.x;
  const int l31 = t & 31, hi = (t >> 5) & 1, w = t >> 6;
  const int gb = blockIdx.x;
  const int chunk = gb >> 3, qt128 = chunk & 15, bh = ((chunk >> 4) << 3) + (gb & 7);
  const int b = bh >> 4, hd = bh & 15;

  // stage Q [128 q][64 k] into sK region, pull B-frags, then region is free
#pragma unroll
  for (int i = 0; i < 4; ++i) {
    int u = i*256 + t;
    int row = u >> 3, gr = (u & 7) ^ (row & 7);
    gld_lds16(QB + ((size_t)(b*SEQ + qt128*128 + row))*DIMN + hd*64 + gr*8,
              sK + u*8);
  }
  __syncthreads();
  const int q = w*32 + l31;
  bf16x8 qf[4];
#pragma unroll
  for (int ks = 0; ks < 4; ++ks)
    qf[ks] = *(bf16x8*)&sK[q*64 + ((ks*2 + hi) ^ (q & 7))*8];

  f32x16 o_acc[2] = {};          // O^T: col = own q (l31), rows d
  float m_run = -1e30f, l_run = 0.f;

  for (int kt = 0; kt < SEQ/128; ++kt) {
    __syncthreads();             // all waves done with prev sK/sV
#pragma unroll
    for (int i = 0; i < 4; ++i) {
      int u = i*256 + t;
      { int row = u >> 3, gr = (u & 7) ^ (row & 7);
        gld_lds16(KB + ((size_t)(b*SEQ + kt*128 + row))*DIMN + hd*64 + gr*8,
                  sK + u*8); }
      { int d = u >> 4, gr = (u & 15) ^ (d & 15);
        gld_lds16(VT + ((size_t)(bh*64 + d))*SEQ + kt*128 + gr*8,
                  sV + u*8); }
    }
    __syncthreads();

    // S^T[kc][q]: 4 kc-tiles of 32. Lane holds col q=l31,
    // rows kc = mt*32 + (r&3) + 8*(r>>2) + 4*hi.
    f32x16 sacc[4] = {};
#pragma unroll
    for (int ks = 0; ks < 4; ++ks)
#pragma unroll
      for (int mt = 0; mt < 4; ++mt) {
        int kc = mt*32 + l31;
        bf16x8 kf = *(bf16x8*)&sK[kc*64 + ((ks*2 + hi) ^ (kc & 7))*8];
        sacc[mt] = __builtin_amdgcn_mfma_f32_32x32x16_bf16(kf, qf[ks], sacc[mt], 0, 0, 0);
      }

    if (!flg[b*16 + kt]) {       // mask slow path (bench: all-valid fast path)
#pragma unroll
      for (int mt = 0; mt < 4; ++mt)
#pragma unroll
        for (int r = 0; r < 16; ++r)
          sacc[mt][r] += mb[b*SEQ + kt*128 + mt*32 + (r&3) + 8*(r>>2) + 4*hi];
    }

    // online softmax: lane owns q = l31; other 64 kc values live in lane^32
    float tmax = -1e30f;
#pragma unroll
    for (int mt = 0; mt < 4; ++mt)
#pragma unroll
      for (int r = 0; r < 16; ++r) tmax = fmaxf(tmax, sacc[mt][r]);
    tmax = fmaxf(tmax, __shfl_xor(tmax, 32));

    if (!__all(tmax <= m_run + 8.f)) {   // defer-max: P bounded by 2^8
      float mnew = fmaxf(m_run, tmax);
      float alpha = exp2f(m_run - mnew);
      l_run *= alpha;
#pragma unroll
      for (int dt = 0; dt < 2; ++dt)
#pragma unroll
        for (int r = 0; r < 16; ++r) o_acc[dt][r] *= alpha;
      m_run = mnew;
    }

    float rs = 0.f;
#pragma unroll
    for (int mt = 0; mt < 4; ++mt)
#pragma unroll
      for (int r = 0; r < 16; ++r) {
        float p = exp2f(sacc[mt][r] - m_run);
        sacc[mt][r] = p;
        rs += p;
      }
    rs += __shfl_xor(rs, 32);
    l_run += rs;

    // P -> bf16 B-frags in-register; O^T += mfma(V^T-frag, P-frag).
#pragma unroll
    for (int mt = 0; mt < 4; ++mt) {
      unsigned wv[8];
#pragma unroll
      for (int i = 0; i < 8; ++i) {
        float plo = sacc[mt][2*i], phi = sacc[mt][2*i+1];
        asm("v_cvt_pk_bf16_f32 %0, %1, %2" : "=v"(wv[i]) : "v"(plo), "v"(phi));
      }
#pragma unroll
      for (int h = 0; h < 2; ++h) {
        unsigned f0 = wv[h*4+0], f1 = wv[h*4+1], f2 = wv[h*4+2], f3 = wv[h*4+3];
        asm volatile("v_permlane32_swap_b32 %0, %1" : "+v"(f0), "+v"(f2));
        asm volatile("v_permlane32_swap_b32 %0, %1" : "+v"(f1), "+v"(f3));
        union { unsigned u[4]; bf16x8 v; } pu;
        pu.u[0] = f0; pu.u[1] = f1; pu.u[2] = f2; pu.u[3] = f3;
        const int kcs = mt*2 + h;      // 16-wide kc step, 0..7
#pragma unroll
        for (int dt = 0; dt < 2; ++dt) {
          int d = dt*32 + l31;
          bf16x8 vf = *(bf16x8*)&sV[d*128 + ((kcs*2 + hi) ^ (d & 15))*8];
          o_acc[dt] = __builtin_amdgcn_mfma_f32_32x32x16_bf16(vf, pu.v, o_acc[dt], 0, 0, 0);
        }
      }
    }
  }

  // epilogue: lane holds O^T col q (its own), rows d = dt*32 + r2 + 8*rg + 4*hi
  float invl = (l_run > 0.f) ? 1.f / l_run : 0.f;
  const size_t rowbase = (size_t)(b*SEQ + qt128*128 + q)*DIMN + hd*64;
#pragma unroll
  for (int dt = 0; dt < 2; ++dt)
#pragma unroll
    for (int rg = 0; rg < 4; ++rg) {
      s16x4 hq, lq;
#pragma unroll
      for (int r2 = 0; r2 < 4; ++r2) {
        float val = o_acc[dt][rg*4 + r2] * invl;
        short hb = f2bf(val);
        hq[r2] = hb;
        lq[r2] = f2bf(val - bf2f(hb));
      }
      size_t idx = rowbase + dt*32 + rg*8 + hi*4;
      *(s16x4*)&CTXh[idx] = hq;
      *(s16x4*)&CTXl[idx] = lq;
    }
}

// ===========================================================================
// Fallback fp32 path for small ws_size.
// ===========================================================================
__global__ __launch_bounds__(256) void gemm_bt(
    const float* __restrict__ X, const float* __restrict__ W,
    const float* __restrict__ bias, float* __restrict__ C,
    int M, int N, int K)
{
  __shared__ __align__(16) float Xs[16][68];
  __shared__ __align__(16) float Ws[16][68];
  const int t  = threadIdx.x;
  const int tx = t & 15, ty = t >> 4;
  const int m0 = blockIdx.y << 6, n0 = blockIdx.x << 6;
  const int ldr = t >> 2;
  const int lk  = (t & 3) << 2;
  float acc[4][4] = {{0.f}};
  const float* Xp = X + (size_t)(m0 + ldr) * K + lk;
  const float* Wp = W + (size_t)(n0 + ldr) * K + lk;
  for (int k0 = 0; k0 < K; k0 += 16) {
    float4 xa = *(const float4*)(Xp + k0);
    float4 wa = *(const float4*)(Wp + k0);
    Xs[lk+0][ldr]=xa.x; Xs[lk+1][ldr]=xa.y; Xs[lk+2][ldr]=xa.z; Xs[lk+3][ldr]=xa.w;
    Ws[lk+0][ldr]=wa.x; Ws[lk+1][ldr]=wa.y; Ws[lk+2][ldr]=wa.z; Ws[lk+3][ldr]=wa.w;
    __syncthreads();
#pragma unroll
    for (int kk = 0; kk < 16; ++kk) {
      float4 a4 = *(const float4*)&Xs[kk][ty<<2];
      float4 b4 = *(const float4*)&Ws[kk][tx<<2];
      float av[4] = {a4.x, a4.y, a4.z, a4.w};
      float bv[4] = {b4.x, b4.y, b4.z, b4.w};
#pragma unroll
      for (int i = 0; i < 4; ++i)
#pragma unroll
        for (int j = 0; j < 4; ++j)
          acc[i][j] = fmaf(av[i], bv[j], acc[i][j]);
    }
    __syncthreads();
  }
  float4 bb4 = *(const float4*)&bias[n0 + (tx<<2)];
  const float bv[4] = {bb4.x, bb4.y, bb4.z, bb4.w};
#pragma unroll
  for (int i = 0; i < 4; ++i) {
    float4 o;
    o.x = acc[i][0]+bv[0]; o.y = acc[i][1]+bv[1];
    o.z = acc[i][2]+bv[2]; o.w = acc[i][3]+bv[3];
    *(float4*)&C[(size_t)(m0 + (ty<<2) + i) * N + n0 + (tx<<2)] = o;
  }
}

__global__ __launch_bounds__(256) void attn_fwd(
    const float* __restrict__ Q, const float* __restrict__ Kbuf,
    const float* __restrict__ Vbuf, const int* __restrict__ mask,
    float* __restrict__ CTX)
{
  __shared__ __align__(16) float Qs[64][68];
  __shared__ __align__(16) float KPs[64][68];
  __shared__ __align__(16) float Vs[64][68];
  const int t  = threadIdx.x;
  const int tx = t & 15, ty = t >> 4;
  const int qt = blockIdx.x;
  const int bh = blockIdx.y;
  const int b  = bh >> 4, h = bh & 15;
  const int ldr = t >> 2;
  const int lcb = (t & 3) << 2;
  const float* Qp = Q + (size_t)(b*SEQ + (qt<<6)) * DIMN + h*DHEAD;
#pragma unroll
  for (int u = 0; u < 4; ++u) {
    int kb = lcb + (u<<4);
    float4 q4 = *(const float4*)(Qp + (size_t)ldr*DIMN + kb);
    Qs[kb+0][ldr]=q4.x; Qs[kb+1][ldr]=q4.y; Qs[kb+2][ldr]=q4.z; Qs[kb+3][ldr]=q4.w;
  }
  float mrow[4], lsum[4], o[4][4];
#pragma unroll
  for (int i = 0; i < 4; ++i) {
    mrow[i] = -1e30f; lsum[i] = 0.f;
#pragma unroll
    for (int j = 0; j < 4; ++j) o[i][j] = 0.f;
  }
  const int qrow0 = ty << 2;
  const int col0  = tx << 2;
  for (int kt = 0; kt < SEQ/64; ++kt) {
    __syncthreads();
    const float* Kp = Kbuf + (size_t)(b*SEQ + (kt<<6)) * DIMN + h*DHEAD;
    const float* Vp = Vbuf + (size_t)(b*SEQ + (kt<<6)) * DIMN + h*DHEAD;
#pragma unroll
    for (int u = 0; u < 4; ++u) {
      int kb = lcb + (u<<4);
      float4 k4 = *(const float4*)(Kp + (size_t)ldr*DIMN + kb);
      KPs[kb+0][ldr]=k4.x; KPs[kb+1][ldr]=k4.y; KPs[kb+2][ldr]=k4.z; KPs[kb+3][ldr]=k4.w;
      float4 v4 = *(const float4*)(Vp + (size_t)ldr*DIMN + kb);
      *(float4*)&Vs[ldr][kb] = v4;
    }
    __syncthreads();
    float s[4][4] = {{0.f}};
#pragma unroll 8
    for (int kk = 0; kk < 64; ++kk) {
      float4 a4 = *(const float4*)&Qs[kk][qrow0];
      float4 b4 = *(const float4*)&KPs[kk][col0];
      float av[4] = {a4.x, a4.y, a4.z, a4.w};
      float bv[4] = {b4.x, b4.y, b4.z, b4.w};
#pragma unroll
      for (int i = 0; i < 4; ++i)
#pragma unroll
        for (int j = 0; j < 4; ++j)
          s[i][j] = fmaf(av[i], bv[j], s[i][j]);
    }
    int mk[4];
#pragma unroll
    for (int j = 0; j < 4; ++j) mk[j] = mask[b*SEQ + (kt<<6) + col0 + j];
    float p[4][4];
#pragma unroll
    for (int i = 0; i < 4; ++i) {
#pragma unroll
      for (int j = 0; j < 4; ++j)
        s[i][j] = mk[j] ? s[i][j]*0.125f : -1e30f;
      float tm = fmaxf(fmaxf(s[i][0], s[i][1]), fmaxf(s[i][2], s[i][3]));
#pragma unroll
      for (int off = 8; off >= 1; off >>= 1)
        tm = fmaxf(tm, __shfl_xor(tm, off, 64));
      float mnew  = fmaxf(mrow[i], tm);
      float aa = __expf(mrow[i] - mnew);
      mrow[i] = mnew;
      float rsum = 0.f;
#pragma unroll
      for (int j = 0; j < 4; ++j) {
        float pv = __expf(s[i][j] - mnew);
        p[i][j] = pv; rsum += pv;
      }
#pragma unroll
      for (int off = 8; off >= 1; off >>= 1)
        rsum += __shfl_xor(rsum, off, 64);
      lsum[i] = lsum[i]*aa + rsum;
#pragma unroll
      for (int j = 0; j < 4; ++j) o[i][j] *= aa;
    }
    __syncthreads();
#pragma unroll
    for (int i = 0; i < 4; ++i)
#pragma unroll
      for (int j = 0; j < 4; ++j)
        KPs[col0 + j][qrow0 + i] = p[i][j];
    __syncthreads();
#pragma unroll 8
    for (int kk = 0; kk < 64; ++kk) {
      float4 a4 = *(const float4*)&KPs[kk][qrow0];
      float4 v4 = *(const float4*)&Vs[kk][col0];
      float av[4] = {a4.x, a4.y, a4.z, a4.w};
      float vv[4] = {v4.x, v4.y, v4.z, v4.w};
#pragma unroll
      for (int i = 0; i < 4; ++i)
#pragma unroll
        for (int j = 0; j < 4; ++j)
          o[i][j] = fmaf(av[i], vv[j], o[i][j]);
    }
  }
  float* Cp = CTX + (size_t)(b*SEQ + (qt<<6)) * DIMN + h*DHEAD;
#pragma unroll
  for (int i = 0; i < 4; ++i) {
    float inv = lsum[i] > 0.f ? 1.0f/lsum[i] : 0.f;
    float4 ov;
    ov.x = o[i][0]*inv; ov.y = o[i][1]*inv;
    ov.z = o[i][2]*inv; ov.w = o[i][3]*inv;
    *(float4*)(Cp + (size_t)(qrow0 + i)*DIMN + col0) = ov;
  }
}

// ---------------------------------------------------------------------------
extern "C" void kernel_launch(void* const* d_in, const int* in_sizes, int n_in,
                              void* d_out, int out_size, void* d_ws, size_t ws_size,
                              hipStream_t stream)
{
  const float* query = (const float*)d_in[0];
  const float* key   = (const float*)d_in[1];
  const float* value = (const float*)d_in[2];
  const int*   mask  = (const int*)d_in[3];
  const float* Wq = (const float*)d_in[4];
  const float* bq = (const float*)d_in[5];
  const float* Wk = (const float*)d_in[6];
  const float* bk = (const float*)d_in[7];
  const float* Wv = (const float*)d_in[8];
  const float* bv = (const float*)d_in[9];
  const float* Wo = (const float*)d_in[10];
  const float* bo = (const float*)d_in[11];
  float* out = (float*)d_out;

  const size_t E  = (size_t)MROWS * DIMN;   // 8,388,608
  const size_t WE = (size_t)DIMN * DIMN;    // 1,048,576

  // ws layout (bytes)
  const size_t o_XB   = 5*WE*2;                 // weights: 10 MB
  const size_t o_QB   = o_XB   + 3*E*2;         // XBq,XBk,XBv: 48 MB
  const size_t o_KB   = o_QB   + E*2;
  const size_t o_VT   = o_KB   + E*2;
  const size_t o_CTXh = o_VT   + E*2;
  const size_t o_CTXl = o_CTXh + E*2;
  const size_t o_MB   = o_CTXl + E*2;
  const size_t o_FLG  = o_MB   + MROWS*4;
  const size_t NEED   = o_FLG  + 64*4;          // ~138 MB

  if (ws_size < NEED) {
    const size_t n = E;
    float* Qb = (float*)d_ws;
    float* Kb = Qb + n;
    float* Vb = Kb + n;
    float* Cb = Vb + n;
    dim3 gg(DIMN/64, MROWS/64), blk(256);
    hipLaunchKernelGGL(gemm_bt, gg, blk, 0, stream, query, Wq, bq, Qb, MROWS, DIMN, DIMN);
    hipLaunchKernelGGL(gemm_bt, gg, blk, 0, stream, key,   Wk, bk, Kb, MROWS, DIMN, DIMN);
    hipLaunchKernelGGL(gemm_bt, gg, blk, 0, stream, value, Wv, bv, Vb, MROWS, DIMN, DIMN);
    dim3 ga(SEQ/64, BSZ*NHEAD);
    hipLaunchKernelGGL(attn_fwd, ga, blk, 0, stream, Qb, Kb, Vb, mask, Cb);
    hipLaunchKernelGGL(gemm_bt, gg, blk, 0, stream, Cb, Wo, bo, out, MROWS, DIMN, DIMN);
    return;
  }

  char* Wp = (char*)d_ws;
  short* WQh = (short*)Wp;
  short* WKh = WQh + WE;
  short* WVh = WQh + 2*WE;
  short* WOh = WQh + 3*WE;
  short* WOl = WQh + 4*WE;
  short* XBq  = (short*)(Wp + o_XB);
  short* XBk  = XBq + E;
  short* XBv  = XBk + E;
  short* QB   = (short*)(Wp + o_QB);
  short* KB   = (short*)(Wp + o_KB);
  short* VT   = (short*)(Wp + o_VT);
  short* CTXh = (short*)(Wp + o_CTXh);
  short* CTXl = (short*)(Wp + o_CTXl);
  float* MB   = (float*)(Wp + o_MB);
  int*   FLG  = (int*)(Wp + o_FLG);

  dim3 blk(256);
  dim3 gW(WE/1024, 4), gX(E/1024, 3);
  dim3 gqkv(DIMN/128, MROWS/128, 3);  // (8, 64, 3)
  dim3 gg(DIMN/128, MROWS/128);       // (8, 64)
  dim3 gat(BSZ*NHEAD*SEQ/128);        // 1024

  hipLaunchKernelGGL(pack_w4, gW, blk, 0, stream, Wq, Wk, Wv, Wo,
                     WQh, WKh, WVh, WOh, WOl, (long)WE);
  hipLaunchKernelGGL(maskbias_k, dim3(MROWS/256), blk, 0, stream, mask, MB, MROWS);
  hipLaunchKernelGGL(mask_flags, dim3(64), dim3(64), 0, stream, mask, FLG);
  hipLaunchKernelGGL(pack_hi3, gX, blk, 0, stream, query, key, value,
                     XBq, XBk, XBv, (long)E);

  hipLaunchKernelGGL(gemm_qkv, gqkv, blk, 0, stream,
                     XBq, XBk, XBv, WQh, WKh, WVh, bq, bk, bv, QB, KB, VT);

  hipLaunchKernelGGL(attn_32, gat, blk, 0, stream, QB, KB, VT, MB, FLG, CTXh, CTXl);

  hipLaunchKernelGGL(gemm_sp, gg, blk, 0, stream, CTXh, CTXl, WOh, WOl, bo, 1.f,
                     out, MROWS, DIMN, DIMN);
}